// Round 1
// baseline (935.348 us; speedup 1.0000x reference)
//
#include <hip/hip_runtime.h>
#include <math.h>

// Problem constants
static constexpr int Bb = 128;    // batch
static constexpr int Tt = 64;     // seq len
static constexpr int Ee = 512;    // embed dim
static constexpr int Hh = 1024;   // hidden
static constexpr int Vv = 10000;  // vocab
static constexpr int G  = 4 * Hh; // 4096 gates
static constexpr int Vpad = 10112; // 79*128, zero-padded vocab rows

typedef __attribute__((ext_vector_type(8))) short short8;
typedef __attribute__((ext_vector_type(4))) float floatx4;

__device__ __forceinline__ unsigned short f2bf(float f) {
    unsigned u = __float_as_uint(f);
    return (unsigned short)((u + 0x7fffu + ((u >> 16) & 1u)) >> 16);  // RNE
}

__device__ __forceinline__ void gload16(const void* g, void* l) {
    __builtin_amdgcn_global_load_lds(
        (const __attribute__((address_space(1))) void*)g,
        (__attribute__((address_space(3))) void*)l, 16, 0, 0);
}

// fast transcendentals (v_exp_f32 + v_rcp_f32; ~1e-6 rel err, far below bf16)
__device__ __forceinline__ float sigmoid_fast(float x) {
    return __builtin_amdgcn_rcpf(1.f + __expf(-x));
}
__device__ __forceinline__ float tanh_fast(float x) {
    float e = __expf(-2.f * fabsf(x));
    float t = (1.f - e) * __builtin_amdgcn_rcpf(1.f + e);
    return copysignf(t, x);
}

// ---------------------------------------------------------------------------
// f32 -> bf16 convert, with zero-padding up to npad elements
// ---------------------------------------------------------------------------
__global__ __launch_bounds__(256)
void cvt_bf16(const float* __restrict__ s, unsigned short* __restrict__ d,
              int n, int npad) {
    int i8 = (blockIdx.x * 256 + threadIdx.x) * 8;
    if (i8 >= npad) return;
    short8 v;
    #pragma unroll
    for (int j = 0; j < 8; ++j) {
        int e = i8 + j;
        float f = (e < n) ? s[e] : 0.f;
        v[j] = (short)f2bf(f);
    }
    *reinterpret_cast<short8*>(d + i8) = v;
}

// ---------------------------------------------------------------------------
// Gather xs[t*B+b, :] = bf16( t==0 ? features[b,:] : embed_W[captions[b,t],:] )
// ---------------------------------------------------------------------------
__global__ __launch_bounds__(256)
void gather_xs(const float* __restrict__ features,
               const int* __restrict__ captions,
               const float* __restrict__ embed_W,
               unsigned short* __restrict__ xs) {
    int idx = blockIdx.x * 256 + threadIdx.x;   // T*B*(E/8)
    int m  = idx >> 6;                          // row, E/8 = 64 chunks per row
    int c8 = (idx & 63) * 8;
    int t = m >> 7;                             // m / B
    int b = m & 127;                            // m % B
    const float* src;
    if (t == 0) {
        src = features + (size_t)b * Ee + c8;
    } else {
        int tok = captions[(size_t)b * Tt + t];
        src = embed_W + (size_t)tok * Ee + c8;
    }
    short8 v;
    #pragma unroll
    for (int j = 0; j < 8; ++j) v[j] = (short)f2bf(src[j]);
    *reinterpret_cast<short8*>(xs + (size_t)m * Ee + c8) = v;
}

// ---------------------------------------------------------------------------
// bf16 MFMA GEMM: C[M,N] = A[M,K] * Bm[N,K]^T (+ epilogue per MODE)
//   MODE 0: C = A*B^T + bias0[n] + bias1[n]
//   MODE 2: out[b,t,v] = A*B^T + bias0[v], m = t*B+b, guard n < N
// Grid flattened with bijective XCD swizzle (nwg % 8 == 0) for B-tile L2 reuse.
// ---------------------------------------------------------------------------
template<int BM, int BN, int MODE>
__global__ __launch_bounds__(256)
void mfma_gemm(const unsigned short* __restrict__ A,
               const unsigned short* __restrict__ Bm,
               int M, int N, int K,
               const float* __restrict__ bias0, const float* __restrict__ bias1,
               float* __restrict__ C) {
    constexpr int BK = 32;
    constexpr int FM = BM / 32;
    constexpr int FN = BN / 32;
    __shared__ unsigned short As[BM * BK];
    __shared__ unsigned short Bs[BN * BK];

    const int nwg = gridDim.x * gridDim.y;
    const int flat = blockIdx.y * gridDim.x + blockIdx.x;
    const int tix = (flat & 7) * (nwg >> 3) + (flat >> 3);
    const int bx = tix % gridDim.x;
    const int by = tix / gridDim.x;

    const int tid  = threadIdx.x;
    const int wid  = tid >> 6;
    const int lane = tid & 63;
    const int wr = wid >> 1, wc = wid & 1;
    const int row0 = bx * BM;
    const int col0 = by * BN;
    const int l15 = lane & 15;
    const int kq  = lane >> 4;

    floatx4 acc[FM][FN];
    #pragma unroll
    for (int i = 0; i < FM; ++i)
        #pragma unroll
        for (int j = 0; j < FN; ++j) acc[i][j] = (floatx4)0.f;

    constexpr int LA = (BM * BK) / (256 * 8);
    constexpr int LB = (BN * BK) / (256 * 8);

    for (int k0 = 0; k0 < K; k0 += BK) {
        #pragma unroll
        for (int i = 0; i < LA; ++i) {
            int e = i * 2048 + tid * 8;
            int r = e >> 5, k = e & 31;
            gload16(A + (size_t)(row0 + r) * K + k0 + k, &As[e]);
        }
        #pragma unroll
        for (int i = 0; i < LB; ++i) {
            int e = i * 2048 + tid * 8;
            int r = e >> 5, k = e & 31;
            gload16(Bm + (size_t)(col0 + r) * K + k0 + k, &Bs[e]);
        }
        __syncthreads();

        short8 af[FM], bfr[FN];
        #pragma unroll
        for (int i = 0; i < FM; ++i) {
            int r = wr * (BM / 2) + i * 16 + l15;
            af[i] = *reinterpret_cast<const short8*>(&As[r * BK + kq * 8]);
        }
        #pragma unroll
        for (int j = 0; j < FN; ++j) {
            int c = wc * (BN / 2) + j * 16 + l15;
            bfr[j] = *reinterpret_cast<const short8*>(&Bs[c * BK + kq * 8]);
        }
        #pragma unroll
        for (int i = 0; i < FM; ++i)
            #pragma unroll
            for (int j = 0; j < FN; ++j)
                acc[i][j] = __builtin_amdgcn_mfma_f32_16x16x32_bf16(
                    af[i], bfr[j], acc[i][j], 0, 0, 0);
        __syncthreads();
    }

    #pragma unroll
    for (int i = 0; i < FM; ++i) {
        #pragma unroll
        for (int j = 0; j < FN; ++j) {
            #pragma unroll
            for (int q = 0; q < 4; ++q) {
                int m = row0 + wr * (BM / 2) + i * 16 + kq * 4 + q;
                int n = col0 + wc * (BN / 2) + j * 16 + l15;
                float v = acc[i][j][q];
                if (MODE == 0) {
                    C[(size_t)m * N + n] = v + bias0[n] + bias1[n];
                } else {
                    if (n < N) {
                        int t = m >> 7, b = m & 127;
                        C[(size_t)b * (Tt * Vv) + (size_t)t * Vv + n] = v + bias0[n];
                    }
                }
            }
        }
    }
}

// ---------------------------------------------------------------------------
// Persistent LSTM recurrence, v6: single h-gather block + xg-after-h.
// 128 WGs x 256 thr. WG w: rows [(w&1)*64,+64), hcols [(w>>1)*16,+16).
// W_hh slice in 128 KB LDS (conflict-free layout, 0 bank conflicts measured).
//
// v6 changes vs v5 (which measured 7.75 us/step, MfmaUtil 5.4%):
//  - v5's xg prefetch was issued BETWEEN h block-1 and h block-2 loads.
//    vmcnt retires IN ORDER, so MFMA block-2 (which reuses the ablk regs and
//    therefore needs the block-2 loads *retired*) had to wait for all 16 xg
//    HBM loads to retire first: ~2000+cy of exposed HBM latency per step,
//    exactly the latency v5 claimed to hide. Plus the b1/b2 split paid the
//    L3 gather round-trip twice.
//  - Now: ONE 32-load h gather (ablk[32], +64 VGPR; launch_bounds(256,1)
//    so the allocator doesn't cap at a multi-wave heuristic — we run 1
//    WG/CU by construction), THEN the xg prefetch, order pinned with
//    sched_barrier(0). All MFMAs need at most vmcnt(16) (xg younger,
//    never gates); fine-grained per-MFMA waits pipeline compute against
//    the arriving gather; xg HBM latency hides under MFMA+epilogue and is
//    drained by the end-of-step __syncthreads.
// Sync (unchanged): write-through sc1 h stores + relaxed flag stores/polls;
// no cache-maintenance ops anywhere in the loop.
// ---------------------------------------------------------------------------
__global__ __launch_bounds__(256, 1)
void lstm_persist(const unsigned short* __restrict__ whhb, // [4096][1024] bf16
                  const float* __restrict__ xg,            // [64*128][4096] f32
                  unsigned short* __restrict__ hsb,        // [64*128][1024] bf16
                  unsigned* __restrict__ flags) {          // [128] stride 32 u32
    __shared__ unsigned short Wlds[64 * Hh];   // 128 KB
    const int tid  = threadIdx.x;
    const int w    = blockIdx.x;
    const int wg_m = w & 1;
    const int wg_n = w >> 1;
    const int wave = tid >> 6;
    const int lane = tid & 63;
    const int l15  = lane & 15;
    const int kq   = lane >> 4;

    // preload W_hh slice: gc = g*16+c  ->  global row g*1024 + wg_n*16 + c
    for (int i = 0; i < 32; ++i) {
        int e8 = i * 256 + tid;
        int q = e8 >> 6, gc = e8 & 63;
        int grow = (gc >> 4) * Hh + wg_n * 16 + (gc & 15);
        short8 v = *reinterpret_cast<const short8*>(
            whhb + (size_t)grow * Hh + q * 8);
        *reinterpret_cast<short8*>(&Wlds[(q * 64 + gc) * 8]) = v;
    }
    __syncthreads();

    const int row_base = wg_m * 64 + wave * 16;
    const int hcol = wg_n * 16 + l15;
    floatx4 c = (floatx4)0.f;

    float xa0[4], xa1[4], xa2[4], xa3[4];   // xg for even steps
    float xb0[4], xb1[4], xb2[4], xb3[4];   // xg for odd steps
    {
        const float* xgt = xg;   // t = 0
        #pragma unroll
        for (int q = 0; q < 4; ++q) {
            int row = row_base + kq * 4 + q;
            const float* xr = xgt + (size_t)row * G + wg_n * 16 + l15;
            xa0[q] = xr[0];
            xa1[q] = xr[Hh];
            xa2[q] = xr[2 * Hh];
            xa3[q] = xr[3 * Hh];
        }
    }

#define LSTM_STEP(T, XC0, XC1, XC2, XC3, XN0, XN1, XN2, XN3)                   \
    do {                                                                       \
        const int t_ = (T);                                                    \
        floatx4 acc0 = (floatx4)0.f, acc1 = (floatx4)0.f;                      \
        floatx4 acc2 = (floatx4)0.f, acc3 = (floatx4)0.f;                      \
        if (t_ > 0) {                                                          \
            if (tid < 64) {                                                    \
                const unsigned* fl = flags + (size_t)(wg_m + tid * 2) * 32;    \
                while (__hip_atomic_load(fl, __ATOMIC_RELAXED,                 \
                                         __HIP_MEMORY_SCOPE_AGENT)             \
                       < (unsigned)t_)                                         \
                    __builtin_amdgcn_s_sleep(1);                               \
            }                                                                  \
            __syncthreads();                                                   \
            asm volatile("" ::: "memory");                                     \
            const unsigned short* hprev = hsb + (size_t)(t_ - 1) * (Bb * Hh);  \
            const short8* arow = reinterpret_cast<const short8*>(              \
                hprev + (size_t)(row_base + l15) * Hh) + kq;                   \
            short8 ablk[32];                                                   \
            _Pragma("unroll")                                                  \
            for (int i = 0; i < 32; ++i) ablk[i] = arow[i * 4];                \
            __builtin_amdgcn_sched_barrier(0);                                 \
            if (t_ + 1 < Tt) {   /* xg prefetch: YOUNGER than all h loads  */  \
                const float* xgt = xg + (size_t)(t_ + 1) * (Bb * G);           \
                _Pragma("unroll")                                              \
                for (int q = 0; q < 4; ++q) {                                  \
                    int row = row_base + kq * 4 + q;                           \
                    const float* xr = xgt + (size_t)row * G + wg_n * 16 + l15; \
                    XN0[q] = xr[0];                                            \
                    XN1[q] = xr[Hh];                                           \
                    XN2[q] = xr[2 * Hh];                                       \
                    XN3[q] = xr[3 * Hh];                                       \
                }                                                              \
            }                                                                  \
            __builtin_amdgcn_sched_barrier(0);                                 \
            _Pragma("unroll")                                                  \
            for (int ks = 0; ks < 32; ++ks) {                                  \
                const short8* bp = reinterpret_cast<const short8*>(            \
                    &Wlds[((ks * 4 + kq) * 64 + l15) * 8]);                    \
                acc0 = __builtin_amdgcn_mfma_f32_16x16x32_bf16(                \
                    ablk[ks], bp[0], acc0, 0, 0, 0);                           \
                acc1 = __builtin_amdgcn_mfma_f32_16x16x32_bf16(                \
                    ablk[ks], bp[16], acc1, 0, 0, 0);                          \
                acc2 = __builtin_amdgcn_mfma_f32_16x16x32_bf16(                \
                    ablk[ks], bp[32], acc2, 0, 0, 0);                          \
                acc3 = __builtin_amdgcn_mfma_f32_16x16x32_bf16(                \
                    ablk[ks], bp[48], acc3, 0, 0, 0);                          \
            }                                                                  \
        } else {                                                               \
            /* t == 0: still prefetch t = 1 */                                 \
            const float* xgt = xg + (size_t)(Bb * G);                          \
            _Pragma("unroll")                                                  \
            for (int q = 0; q < 4; ++q) {                                      \
                int row = row_base + kq * 4 + q;                               \
                const float* xr = xgt + (size_t)row * G + wg_n * 16 + l15;     \
                XN0[q] = xr[0];                                                \
                XN1[q] = xr[Hh];                                               \
                XN2[q] = xr[2 * Hh];                                           \
                XN3[q] = xr[3 * Hh];                                           \
            }                                                                  \
        }                                                                      \
        unsigned short* ht = hsb + (size_t)t_ * (Bb * Hh);                     \
        _Pragma("unroll")                                                      \
        for (int q = 0; q < 4; ++q) {                                          \
            int row = row_base + kq * 4 + q;                                   \
            float gi = acc0[q] + XC0[q];                                       \
            float gf = acc1[q] + XC1[q];                                       \
            float gg = acc2[q] + XC2[q];                                       \
            float go = acc3[q] + XC3[q];                                       \
            float si = sigmoid_fast(gi);                                       \
            float sf = sigmoid_fast(gf);                                       \
            float tg = tanh_fast(gg);                                          \
            float so = sigmoid_fast(go);                                       \
            float cn = sf * c[q] + si * tg;                                    \
            c[q] = cn;                                                         \
            float h = so * tanh_fast(cn);                                      \
            __hip_atomic_store(&ht[(size_t)row * Hh + hcol], f2bf(h),          \
                               __ATOMIC_RELAXED, __HIP_MEMORY_SCOPE_AGENT);    \
        }                                                                      \
        if (t_ < Tt - 1) {                                                     \
            __syncthreads();  /* vmcnt(0): sc1 h stores ack'd at L3 */         \
            if (tid == 0) {                                                    \
                __hip_atomic_store(flags + (size_t)w * 32,                     \
                                   (unsigned)(t_ + 1), __ATOMIC_RELAXED,       \
                                   __HIP_MEMORY_SCOPE_AGENT);                  \
            }                                                                  \
        }                                                                      \
    } while (0)

    for (int tt = 0; tt < Tt; tt += 2) {
        LSTM_STEP(tt,     xa0, xa1, xa2, xa3, xb0, xb1, xb2, xb3);
        LSTM_STEP(tt + 1, xb0, xb1, xb2, xb3, xa0, xa1, xa2, xa3);
    }
#undef LSTM_STEP
}

// ---------------------------------------------------------------------------
extern "C" void kernel_launch(void* const* d_in, const int* in_sizes, int n_in,
                              void* d_out, int out_size, void* d_ws, size_t ws_size,
                              hipStream_t stream) {
    const float* features = (const float*)d_in[0];
    const int*   captions = (const int*)d_in[1];
    const float* embed_W  = (const float*)d_in[2];
    const float* W_ih     = (const float*)d_in[3];
    const float* W_hh     = (const float*)d_in[4];
    const float* b_ih     = (const float*)d_in[5];
    const float* b_hh     = (const float*)d_in[6];
    const float* fc_W     = (const float*)d_in[7];
    const float* fc_b     = (const float*)d_in[8];
    float* out = (float*)d_out;

    unsigned short* xsb  = (unsigned short*)d_ws;          // [8192][512]
    unsigned short* wihb = xsb  + (size_t)Tt * Bb * Ee;    // [4096][512]
    unsigned short* whhb = wihb + (size_t)G * Ee;          // [4096][1024]
    unsigned short* fcwb = whhb + (size_t)G * Hh;          // [10112][1024]
    unsigned short* hsb  = fcwb + (size_t)Vpad * Hh;       // [8192][1024]
    float* xg = (float*)(hsb + (size_t)Tt * Bb * Hh);      // [8192][4096]
    unsigned* flags = (unsigned*)(xg + (size_t)Tt * Bb * G); // 128*32 u32

    hipMemsetAsync(flags, 0, 128 * 32 * sizeof(unsigned), stream);

    // 1) weight conversions + input gather
    cvt_bf16<<<(G * Ee / 8) / 256, 256, 0, stream>>>(W_ih, wihb, G * Ee, G * Ee);
    cvt_bf16<<<(G * Hh / 8) / 256, 256, 0, stream>>>(W_hh, whhb, G * Hh, G * Hh);
    cvt_bf16<<<(Vpad * Hh / 8) / 256, 256, 0, stream>>>(fc_W, fcwb, Vv * Hh, Vpad * Hh);
    gather_xs<<<(Tt * Bb * (Ee / 8)) / 256, 256, 0, stream>>>(
        features, captions, embed_W, xsb);

    // 2) x_gates = xs @ W_ih^T + b_ih + b_hh   (M=8192, N=4096, K=512)
    {
        dim3 grid(8192 / 128, G / 128);   // 2048 wgs (%8 == 0)
        mfma_gemm<128, 128, 0><<<grid, 256, 0, stream>>>(
            xsb, wihb, 8192, G, Ee, b_ih, b_hh, xg);
    }

    // 3) persistent LSTM recurrence (one launch, 64 steps)
    lstm_persist<<<128, 256, 0, stream>>>(whhb, xg, hsb, flags);

    // 4) out[b,t,v] = hs @ fc_W^T + fc_b   (M=8192, N=10000(pad 10112), K=1024)
    {
        dim3 grid(8192 / 128, Vpad / 128);  // 5056 wgs (%8 == 0)
        mfma_gemm<128, 128, 2><<<grid, 256, 0, stream>>>(
            hsb, fcwb, 8192, Vv, Hh, fc_b, nullptr, out);
    }
}

// Round 2
// 930.527 us; speedup vs baseline: 1.0052x; 1.0052x over previous
//
#include <hip/hip_runtime.h>
#include <math.h>

// Problem constants
static constexpr int Bb = 128;    // batch
static constexpr int Tt = 64;     // seq len
static constexpr int Ee = 512;    // embed dim
static constexpr int Hh = 1024;   // hidden
static constexpr int Vv = 10000;  // vocab
static constexpr int G  = 4 * Hh; // 4096 gates
static constexpr int Vpad = 10112; // 79*128, zero-padded vocab rows

typedef __attribute__((ext_vector_type(8))) short short8;
typedef __attribute__((ext_vector_type(4))) float floatx4;

__device__ __forceinline__ unsigned short f2bf(float f) {
    unsigned u = __float_as_uint(f);
    return (unsigned short)((u + 0x7fffu + ((u >> 16) & 1u)) >> 16);  // RNE
}

__device__ __forceinline__ void gload16(const void* g, void* l) {
    __builtin_amdgcn_global_load_lds(
        (const __attribute__((address_space(1))) void*)g,
        (__attribute__((address_space(3))) void*)l, 16, 0, 0);
}

// fast transcendentals (v_exp_f32 + v_rcp_f32; ~1e-6 rel err, far below bf16)
__device__ __forceinline__ float sigmoid_fast(float x) {
    return __builtin_amdgcn_rcpf(1.f + __expf(-x));
}
__device__ __forceinline__ float tanh_fast(float x) {
    float e = __expf(-2.f * fabsf(x));
    float t = (1.f - e) * __builtin_amdgcn_rcpf(1.f + e);
    return copysignf(t, x);
}

// ---------------------------------------------------------------------------
// f32 -> bf16 convert, with zero-padding up to npad elements
// ---------------------------------------------------------------------------
__global__ __launch_bounds__(256)
void cvt_bf16(const float* __restrict__ s, unsigned short* __restrict__ d,
              int n, int npad) {
    int i8 = (blockIdx.x * 256 + threadIdx.x) * 8;
    if (i8 >= npad) return;
    short8 v;
    #pragma unroll
    for (int j = 0; j < 8; ++j) {
        int e = i8 + j;
        float f = (e < n) ? s[e] : 0.f;
        v[j] = (short)f2bf(f);
    }
    *reinterpret_cast<short8*>(d + i8) = v;
}

// ---------------------------------------------------------------------------
// Gather xs[t*B+b, :] = bf16( t==0 ? features[b,:] : embed_W[captions[b,t],:] )
// ---------------------------------------------------------------------------
__global__ __launch_bounds__(256)
void gather_xs(const float* __restrict__ features,
               const int* __restrict__ captions,
               const float* __restrict__ embed_W,
               unsigned short* __restrict__ xs) {
    int idx = blockIdx.x * 256 + threadIdx.x;   // T*B*(E/8)
    int m  = idx >> 6;                          // row, E/8 = 64 chunks per row
    int c8 = (idx & 63) * 8;
    int t = m >> 7;                             // m / B
    int b = m & 127;                            // m % B
    const float* src;
    if (t == 0) {
        src = features + (size_t)b * Ee + c8;
    } else {
        int tok = captions[(size_t)b * Tt + t];
        src = embed_W + (size_t)tok * Ee + c8;
    }
    short8 v;
    #pragma unroll
    for (int j = 0; j < 8; ++j) v[j] = (short)f2bf(src[j]);
    *reinterpret_cast<short8*>(xs + (size_t)m * Ee + c8) = v;
}

// ---------------------------------------------------------------------------
// bf16 MFMA GEMM: C[M,N] = A[M,K] * Bm[N,K]^T (+ epilogue per MODE)
//   MODE 0: C = A*B^T + bias0[n] + bias1[n]; A row-major [M][K]
//   MODE 2: out[b,t,v] = A*B^T + bias0[v], m = t*B+b, guard n < N;
//           A is the BLOCKED h layout: [t][hb=K/16][row=128][c=16]
// Grid flattened with bijective XCD swizzle (nwg % 8 == 0) for B-tile L2 reuse.
// ---------------------------------------------------------------------------
template<int BM, int BN, int MODE>
__global__ __launch_bounds__(256)
void mfma_gemm(const unsigned short* __restrict__ A,
               const unsigned short* __restrict__ Bm,
               int M, int N, int K,
               const float* __restrict__ bias0, const float* __restrict__ bias1,
               float* __restrict__ C) {
    constexpr int BK = 32;
    constexpr int FM = BM / 32;
    constexpr int FN = BN / 32;
    __shared__ unsigned short As[BM * BK];
    __shared__ unsigned short Bs[BN * BK];

    const int nwg = gridDim.x * gridDim.y;
    const int flat = blockIdx.y * gridDim.x + blockIdx.x;
    const int tix = (flat & 7) * (nwg >> 3) + (flat >> 3);
    const int bx = tix % gridDim.x;
    const int by = tix / gridDim.x;

    const int tid  = threadIdx.x;
    const int wid  = tid >> 6;
    const int lane = tid & 63;
    const int wr = wid >> 1, wc = wid & 1;
    const int row0 = bx * BM;
    const int col0 = by * BN;
    const int l15 = lane & 15;
    const int kq  = lane >> 4;

    floatx4 acc[FM][FN];
    #pragma unroll
    for (int i = 0; i < FM; ++i)
        #pragma unroll
        for (int j = 0; j < FN; ++j) acc[i][j] = (floatx4)0.f;

    constexpr int LA = (BM * BK) / (256 * 8);
    constexpr int LB = (BN * BK) / (256 * 8);

    for (int k0 = 0; k0 < K; k0 += BK) {
        #pragma unroll
        for (int i = 0; i < LA; ++i) {
            int e = i * 2048 + tid * 8;
            int r = e >> 5, k = e & 31;
            int m = row0 + r, kk = k0 + k;
            size_t a_off;
            if (MODE == 2) {
                // blocked h: [t][hb][row 128][c 16]
                a_off = (size_t)(m >> 7) * ((size_t)(1024 / 16) * 128 * 16)
                      + (size_t)(kk >> 4) * (128 * 16)
                      + (size_t)(m & 127) * 16 + (kk & 15);
            } else {
                a_off = (size_t)m * K + kk;
            }
            gload16(A + a_off, &As[e]);
        }
        #pragma unroll
        for (int i = 0; i < LB; ++i) {
            int e = i * 2048 + tid * 8;
            int r = e >> 5, k = e & 31;
            gload16(Bm + (size_t)(col0 + r) * K + k0 + k, &Bs[e]);
        }
        __syncthreads();

        short8 af[FM], bfr[FN];
        #pragma unroll
        for (int i = 0; i < FM; ++i) {
            int r = wr * (BM / 2) + i * 16 + l15;
            af[i] = *reinterpret_cast<const short8*>(&As[r * BK + kq * 8]);
        }
        #pragma unroll
        for (int j = 0; j < FN; ++j) {
            int c = wc * (BN / 2) + j * 16 + l15;
            bfr[j] = *reinterpret_cast<const short8*>(&Bs[c * BK + kq * 8]);
        }
        #pragma unroll
        for (int i = 0; i < FM; ++i)
            #pragma unroll
            for (int j = 0; j < FN; ++j)
                acc[i][j] = __builtin_amdgcn_mfma_f32_16x16x32_bf16(
                    af[i], bfr[j], acc[i][j], 0, 0, 0);
        __syncthreads();
    }

    #pragma unroll
    for (int i = 0; i < FM; ++i) {
        #pragma unroll
        for (int j = 0; j < FN; ++j) {
            #pragma unroll
            for (int q = 0; q < 4; ++q) {
                int m = row0 + wr * (BM / 2) + i * 16 + kq * 4 + q;
                int n = col0 + wc * (BN / 2) + j * 16 + l15;
                float v = acc[i][j][q];
                if (MODE == 0) {
                    C[(size_t)m * N + n] = v + bias0[n] + bias1[n];
                } else {
                    if (n < N) {
                        int t = m >> 7, b = m & 127;
                        C[(size_t)b * (Tt * Vv) + (size_t)t * Vv + n] = v + bias0[n];
                    }
                }
            }
        }
    }
}

// ---------------------------------------------------------------------------
// Persistent LSTM recurrence, v7.
// 128 WGs x 256 thr. WG w: rows [(w&1)*64,+64), hcols [(w>>1)*16,+16).
// W_hh slice in 128 KB LDS. Two independent 64-WG cohorts (wg_m).
//
// v7 vs v5 (7.75 us/step) — attacks sync/store contention, not the gather:
//  - COUNTER-TREE SYNC: 8 monotonic counters per cohort (8 producers inc
//    each, 64B-strided lines). Consumer: 8 threads poll counter[g] >= 8*t.
//    Replaces 8192 concurrent sc1 pollers on 128 lines with 1024 on 16
//    lines (64x less L3 poll traffic). Monotonic => no per-step storage,
//    no reset. Lockstep induction: first time sum==8t, every producer ==t.
//  - BLOCKED h LAYOUT [t][hb=64][row=128][c=16] + LDS-transposed stores:
//    epilogue scatters h into a 3KB LDS stage, then 128 threads emit ONE
//    global_store_dwordx4 sc1 each (2KB fully contiguous per WG) instead
//    of 1024 scattered 2B sc1 stores. 8x fewer write-through transactions
//    on the ack path. Consumer gather chunk (ks,kq) maps to block
//    2ks+(kq>>1), 16B offset (kq&1)*16 — same 32 b128 loads per lane.
//  - xg PREFETCH LAST: issued after the h stores (youngest VMEM), pinned
//    with sched_barrier(0). Tail: s_waitcnt vmcnt(16) (h store ack'd, xg
//    still in flight) -> raw s_barrier -> tid0 counter inc. MFMA phase
//    never waits on HBM; xg drains during the next step's poll phase.
//  - v6's ablk[32] reverted (it spilled: 190+ live VGPRs pinned by fences).
// ---------------------------------------------------------------------------
__global__ __launch_bounds__(256)
void lstm_persist(const unsigned short* __restrict__ whhb, // [4096][1024] bf16
                  const float* __restrict__ xg,            // [64*128][4096] f32
                  unsigned short* __restrict__ hsb,        // blocked, see above
                  unsigned* __restrict__ flags) {          // 16 counters, 64B stride
    __shared__ unsigned short Wlds[64 * Hh];   // 128 KB
    __shared__ unsigned short stage[64 * 24];  // 3 KB h-transpose stage
    const int tid  = threadIdx.x;
    const int w    = blockIdx.x;
    const int wg_m = w & 1;
    const int wg_n = w >> 1;
    const int wave = tid >> 6;
    const int lane = tid & 63;
    const int l15  = lane & 15;
    const int kq   = lane >> 4;

    // preload W_hh slice: gc = g*16+c  ->  global row g*1024 + wg_n*16 + c
    for (int i = 0; i < 32; ++i) {
        int e8 = i * 256 + tid;
        int q = e8 >> 6, gc = e8 & 63;
        int grow = (gc >> 4) * Hh + wg_n * 16 + (gc & 15);
        short8 v = *reinterpret_cast<const short8*>(
            whhb + (size_t)grow * Hh + q * 8);
        *reinterpret_cast<short8*>(&Wlds[(q * 64 + gc) * 8]) = v;
    }
    __syncthreads();

    const int row_base = wg_m * 64 + wave * 16;
    unsigned* myctr = flags + (size_t)(wg_m * 8 + (wg_n >> 3)) * 16;
    floatx4 c = (floatx4)0.f;

    float xa0[4], xa1[4], xa2[4], xa3[4];   // xg for even steps
    float xb0[4], xb1[4], xb2[4], xb3[4];   // xg for odd steps
    {
        const float* xgt = xg;   // t = 0
        #pragma unroll
        for (int q = 0; q < 4; ++q) {
            int row = row_base + kq * 4 + q;
            const float* xr = xgt + (size_t)row * G + wg_n * 16 + l15;
            xa0[q] = xr[0];
            xa1[q] = xr[Hh];
            xa2[q] = xr[2 * Hh];
            xa3[q] = xr[3 * Hh];
        }
    }

#define LSTM_STEP(T, XC0, XC1, XC2, XC3, XN0, XN1, XN2, XN3)                   \
    do {                                                                       \
        const int t_ = (T);                                                    \
        floatx4 acc0 = (floatx4)0.f, acc1 = (floatx4)0.f;                      \
        floatx4 acc2 = (floatx4)0.f, acc3 = (floatx4)0.f;                      \
        if (t_ > 0) {                                                          \
            if (tid < 8) {                                                     \
                const unsigned* fl = flags + (size_t)(wg_m * 8 + tid) * 16;    \
                unsigned need = 8u * (unsigned)t_;                             \
                while (__hip_atomic_load(fl, __ATOMIC_RELAXED,                 \
                                         __HIP_MEMORY_SCOPE_AGENT) < need)     \
                    __builtin_amdgcn_s_sleep(1);                               \
            }                                                                  \
            __syncthreads();                                                   \
            asm volatile("" ::: "memory");                                     \
            /* blocked gather: chunk ks -> block 2ks+(kq>>1), off (kq&1)*16 */ \
            const short8* arow = reinterpret_cast<const short8*>(hsb)          \
                + (size_t)(t_ - 1) * 16384                                     \
                + (size_t)(row_base + l15) * 2 + (kq & 1) + (kq >> 1) * 256;   \
            short8 ablk[16];                                                   \
            _Pragma("unroll")                                                  \
            for (int i = 0; i < 16; ++i) ablk[i] = arow[i * 512];              \
            _Pragma("unroll")                                                  \
            for (int ks = 0; ks < 16; ++ks) {                                  \
                const short8* bp = reinterpret_cast<const short8*>(            \
                    &Wlds[((ks * 4 + kq) * 64 + l15) * 8]);                    \
                acc0 = __builtin_amdgcn_mfma_f32_16x16x32_bf16(                \
                    ablk[ks], bp[0], acc0, 0, 0, 0);                           \
                acc1 = __builtin_amdgcn_mfma_f32_16x16x32_bf16(                \
                    ablk[ks], bp[16], acc1, 0, 0, 0);                          \
                acc2 = __builtin_amdgcn_mfma_f32_16x16x32_bf16(                \
                    ablk[ks], bp[32], acc2, 0, 0, 0);                          \
                acc3 = __builtin_amdgcn_mfma_f32_16x16x32_bf16(                \
                    ablk[ks], bp[48], acc3, 0, 0, 0);                          \
            }                                                                  \
            _Pragma("unroll")                                                  \
            for (int i = 0; i < 16; ++i) ablk[i] = arow[(16 + i) * 512];       \
            _Pragma("unroll")                                                  \
            for (int ks = 16; ks < 32; ++ks) {                                 \
                const short8* bp = reinterpret_cast<const short8*>(            \
                    &Wlds[((ks * 4 + kq) * 64 + l15) * 8]);                    \
                acc0 = __builtin_amdgcn_mfma_f32_16x16x32_bf16(                \
                    ablk[ks - 16], bp[0], acc0, 0, 0, 0);                      \
                acc1 = __builtin_amdgcn_mfma_f32_16x16x32_bf16(                \
                    ablk[ks - 16], bp[16], acc1, 0, 0, 0);                     \
                acc2 = __builtin_amdgcn_mfma_f32_16x16x32_bf16(                \
                    ablk[ks - 16], bp[32], acc2, 0, 0, 0);                     \
                acc3 = __builtin_amdgcn_mfma_f32_16x16x32_bf16(                \
                    ablk[ks - 16], bp[48], acc3, 0, 0, 0);                     \
            }                                                                  \
        }                                                                      \
        _Pragma("unroll")                                                      \
        for (int q = 0; q < 4; ++q) {                                          \
            float gi = acc0[q] + XC0[q];                                       \
            float gf = acc1[q] + XC1[q];                                       \
            float gg = acc2[q] + XC2[q];                                       \
            float go = acc3[q] + XC3[q];                                       \
            float si = sigmoid_fast(gi);                                       \
            float sf = sigmoid_fast(gf);                                       \
            float tg = tanh_fast(gg);                                          \
            float so = sigmoid_fast(go);                                       \
            float cn = sf * c[q] + si * tg;                                    \
            c[q] = cn;                                                         \
            float h = so * tanh_fast(cn);                                      \
            stage[(wave * 16 + kq * 4 + q) * 24 + l15] = f2bf(h);              \
        }                                                                      \
        __syncthreads();   /* stage visible; no VMEM outstanding here */       \
        if (tid < 128) {                                                       \
            const int rel = tid >> 1, half = tid & 1;                          \
            short8 sv = *reinterpret_cast<const short8*>(                      \
                &stage[rel * 24 + half * 8]);                                  \
            const unsigned short* gp = hsb + (size_t)t_ * 131072               \
                + (size_t)((wg_n * 128 + wg_m * 64 + rel) * 16 + half * 8);    \
            asm volatile("global_store_dwordx4 %0, %1, off sc1"                \
                         :: "v"((unsigned long long)(uintptr_t)gp), "v"(sv)    \
                         : "memory");                                          \
        }                                                                      \
        __builtin_amdgcn_sched_barrier(0);                                     \
        if (t_ + 1 < Tt) {   /* xg prefetch: YOUNGEST VMEM (after stores) */   \
            const float* xgt = xg + (size_t)(t_ + 1) * (Bb * G);               \
            _Pragma("unroll")                                                  \
            for (int q = 0; q < 4; ++q) {                                      \
                int row = row_base + kq * 4 + q;                               \
                const float* xr = xgt + (size_t)row * G + wg_n * 16 + l15;     \
                XN0[q] = xr[0];                                                \
                XN1[q] = xr[Hh];                                               \
                XN2[q] = xr[2 * Hh];                                           \
                XN3[q] = xr[3 * Hh];                                           \
            }                                                                  \
        }                                                                      \
        __builtin_amdgcn_sched_barrier(0);                                     \
        if (t_ < Tt - 1) {                                                     \
            if (tid < 128)   /* wave-uniform: waves 0,1 */                     \
                asm volatile("s_waitcnt vmcnt(16)" ::: "memory");              \
            __builtin_amdgcn_sched_barrier(0);                                 \
            __builtin_amdgcn_s_barrier();                                      \
            __builtin_amdgcn_sched_barrier(0);                                 \
            if (tid == 0)                                                      \
                __hip_atomic_fetch_add(myctr, 1u, __ATOMIC_RELAXED,            \
                                       __HIP_MEMORY_SCOPE_AGENT);              \
        }                                                                      \
    } while (0)

    for (int tt = 0; tt < Tt; tt += 2) {
        LSTM_STEP(tt,     xa0, xa1, xa2, xa3, xb0, xb1, xb2, xb3);
        LSTM_STEP(tt + 1, xb0, xb1, xb2, xb3, xa0, xa1, xa2, xa3);
    }
#undef LSTM_STEP
}

// ---------------------------------------------------------------------------
extern "C" void kernel_launch(void* const* d_in, const int* in_sizes, int n_in,
                              void* d_out, int out_size, void* d_ws, size_t ws_size,
                              hipStream_t stream) {
    const float* features = (const float*)d_in[0];
    const int*   captions = (const int*)d_in[1];
    const float* embed_W  = (const float*)d_in[2];
    const float* W_ih     = (const float*)d_in[3];
    const float* W_hh     = (const float*)d_in[4];
    const float* b_ih     = (const float*)d_in[5];
    const float* b_hh     = (const float*)d_in[6];
    const float* fc_W     = (const float*)d_in[7];
    const float* fc_b     = (const float*)d_in[8];
    float* out = (float*)d_out;

    unsigned short* xsb  = (unsigned short*)d_ws;          // [8192][512]
    unsigned short* wihb = xsb  + (size_t)Tt * Bb * Ee;    // [4096][512]
    unsigned short* whhb = wihb + (size_t)G * Ee;          // [4096][1024]
    unsigned short* fcwb = whhb + (size_t)G * Hh;          // [10112][1024]
    unsigned short* hsb  = fcwb + (size_t)Vpad * Hh;       // [64][64][128][16] blocked
    float* xg = (float*)(hsb + (size_t)Tt * Bb * Hh);      // [8192][4096]
    unsigned* flags = (unsigned*)(xg + (size_t)Tt * Bb * G); // 16 ctrs, 64B stride

    hipMemsetAsync(flags, 0, 128 * 32 * sizeof(unsigned), stream);

    // 1) weight conversions + input gather
    cvt_bf16<<<(G * Ee / 8) / 256, 256, 0, stream>>>(W_ih, wihb, G * Ee, G * Ee);
    cvt_bf16<<<(G * Hh / 8) / 256, 256, 0, stream>>>(W_hh, whhb, G * Hh, G * Hh);
    cvt_bf16<<<(Vpad * Hh / 8) / 256, 256, 0, stream>>>(fc_W, fcwb, Vv * Hh, Vpad * Hh);
    gather_xs<<<(Tt * Bb * (Ee / 8)) / 256, 256, 0, stream>>>(
        features, captions, embed_W, xsb);

    // 2) x_gates = xs @ W_ih^T + b_ih + b_hh   (M=8192, N=4096, K=512)
    {
        dim3 grid(8192 / 128, G / 128);   // 2048 wgs (%8 == 0)
        mfma_gemm<128, 128, 0><<<grid, 256, 0, stream>>>(
            xsb, wihb, 8192, G, Ee, b_ih, b_hh, xg);
    }

    // 3) persistent LSTM recurrence (one launch, 64 steps)
    lstm_persist<<<128, 256, 0, stream>>>(whhb, xg, hsb, flags);

    // 4) out[b,t,v] = hs @ fc_W^T + fc_b   (M=8192, N=10000(pad 10112), K=1024)
    //    A (hsb) is in the blocked layout; MODE 2 addressing handles it.
    {
        dim3 grid(8192 / 128, Vpad / 128);  // 5056 wgs (%8 == 0)
        mfma_gemm<128, 128, 2><<<grid, 256, 0, stream>>>(
            hsb, fcwb, 8192, Vv, Hh, fc_b, nullptr, out);
    }
}

// Round 3
// 751.083 us; speedup vs baseline: 1.2453x; 1.2389x over previous
//
#include <hip/hip_runtime.h>
#include <math.h>

// Problem constants
static constexpr int Bb = 128;    // batch
static constexpr int Tt = 64;     // seq len
static constexpr int Ee = 512;    // embed dim
static constexpr int Hh = 1024;   // hidden
static constexpr int Vv = 10000;  // vocab
static constexpr int G  = 4 * Hh; // 4096 gates
static constexpr int Vpad = 10112; // 79*128, zero-padded vocab rows

typedef __attribute__((ext_vector_type(8))) short short8;
typedef __attribute__((ext_vector_type(4))) float floatx4;

__device__ __forceinline__ unsigned short f2bf(float f) {
    unsigned u = __float_as_uint(f);
    return (unsigned short)((u + 0x7fffu + ((u >> 16) & 1u)) >> 16);  // RNE
}

__device__ __forceinline__ void gload16(const void* g, void* l) {
    __builtin_amdgcn_global_load_lds(
        (const __attribute__((address_space(1))) void*)g,
        (__attribute__((address_space(3))) void*)l, 16, 0, 0);
}

// fast transcendentals (v_exp_f32 + v_rcp_f32; ~1e-6 rel err, far below bf16)
__device__ __forceinline__ float sigmoid_fast(float x) {
    return __builtin_amdgcn_rcpf(1.f + __expf(-x));
}
__device__ __forceinline__ float tanh_fast(float x) {
    float e = __expf(-2.f * fabsf(x));
    float t = (1.f - e) * __builtin_amdgcn_rcpf(1.f + e);
    return copysignf(t, x);
}

// ---------------------------------------------------------------------------
// f32 -> bf16 convert, with zero-padding up to npad elements
// ---------------------------------------------------------------------------
__global__ __launch_bounds__(256)
void cvt_bf16(const float* __restrict__ s, unsigned short* __restrict__ d,
              int n, int npad) {
    int i8 = (blockIdx.x * 256 + threadIdx.x) * 8;
    if (i8 >= npad) return;
    short8 v;
    #pragma unroll
    for (int j = 0; j < 8; ++j) {
        int e = i8 + j;
        float f = (e < n) ? s[e] : 0.f;
        v[j] = (short)f2bf(f);
    }
    *reinterpret_cast<short8*>(d + i8) = v;
}

// ---------------------------------------------------------------------------
// Gather xs[t*B+b, :] = bf16( t==0 ? features[b,:] : embed_W[captions[b,t],:] )
// ---------------------------------------------------------------------------
__global__ __launch_bounds__(256)
void gather_xs(const float* __restrict__ features,
               const int* __restrict__ captions,
               const float* __restrict__ embed_W,
               unsigned short* __restrict__ xs) {
    int idx = blockIdx.x * 256 + threadIdx.x;   // T*B*(E/8)
    int m  = idx >> 6;                          // row, E/8 = 64 chunks per row
    int c8 = (idx & 63) * 8;
    int t = m >> 7;                             // m / B
    int b = m & 127;                            // m % B
    const float* src;
    if (t == 0) {
        src = features + (size_t)b * Ee + c8;
    } else {
        int tok = captions[(size_t)b * Tt + t];
        src = embed_W + (size_t)tok * Ee + c8;
    }
    short8 v;
    #pragma unroll
    for (int j = 0; j < 8; ++j) v[j] = (short)f2bf(src[j]);
    *reinterpret_cast<short8*>(xs + (size_t)m * Ee + c8) = v;
}

// ---------------------------------------------------------------------------
// bf16 MFMA GEMM: C[M,N] = A[M,K] * Bm[N,K]^T (+ epilogue per MODE)
//   MODE 0: C = A*B^T + bias0[n] + bias1[n]
//   MODE 2: out[b,t,v] = A*B^T + bias0[v], m = t*B+b, guard n < N
// Grid flattened with bijective XCD swizzle (nwg % 8 == 0) for B-tile L2 reuse.
// ---------------------------------------------------------------------------
template<int BM, int BN, int MODE>
__global__ __launch_bounds__(256)
void mfma_gemm(const unsigned short* __restrict__ A,
               const unsigned short* __restrict__ Bm,
               int M, int N, int K,
               const float* __restrict__ bias0, const float* __restrict__ bias1,
               float* __restrict__ C) {
    constexpr int BK = 32;
    constexpr int FM = BM / 32;
    constexpr int FN = BN / 32;
    __shared__ unsigned short As[BM * BK];
    __shared__ unsigned short Bs[BN * BK];

    const int nwg = gridDim.x * gridDim.y;
    const int flat = blockIdx.y * gridDim.x + blockIdx.x;
    const int tix = (flat & 7) * (nwg >> 3) + (flat >> 3);
    const int bx = tix % gridDim.x;
    const int by = tix / gridDim.x;

    const int tid  = threadIdx.x;
    const int wid  = tid >> 6;
    const int lane = tid & 63;
    const int wr = wid >> 1, wc = wid & 1;
    const int row0 = bx * BM;
    const int col0 = by * BN;
    const int l15 = lane & 15;
    const int kq  = lane >> 4;

    floatx4 acc[FM][FN];
    #pragma unroll
    for (int i = 0; i < FM; ++i)
        #pragma unroll
        for (int j = 0; j < FN; ++j) acc[i][j] = (floatx4)0.f;

    constexpr int LA = (BM * BK) / (256 * 8);
    constexpr int LB = (BN * BK) / (256 * 8);

    for (int k0 = 0; k0 < K; k0 += BK) {
        #pragma unroll
        for (int i = 0; i < LA; ++i) {
            int e = i * 2048 + tid * 8;
            int r = e >> 5, k = e & 31;
            gload16(A + (size_t)(row0 + r) * K + k0 + k, &As[e]);
        }
        #pragma unroll
        for (int i = 0; i < LB; ++i) {
            int e = i * 2048 + tid * 8;
            int r = e >> 5, k = e & 31;
            gload16(Bm + (size_t)(col0 + r) * K + k0 + k, &Bs[e]);
        }
        __syncthreads();

        short8 af[FM], bfr[FN];
        #pragma unroll
        for (int i = 0; i < FM; ++i) {
            int r = wr * (BM / 2) + i * 16 + l15;
            af[i] = *reinterpret_cast<const short8*>(&As[r * BK + kq * 8]);
        }
        #pragma unroll
        for (int j = 0; j < FN; ++j) {
            int c = wc * (BN / 2) + j * 16 + l15;
            bfr[j] = *reinterpret_cast<const short8*>(&Bs[c * BK + kq * 8]);
        }
        #pragma unroll
        for (int i = 0; i < FM; ++i)
            #pragma unroll
            for (int j = 0; j < FN; ++j)
                acc[i][j] = __builtin_amdgcn_mfma_f32_16x16x32_bf16(
                    af[i], bfr[j], acc[i][j], 0, 0, 0);
        __syncthreads();
    }

    #pragma unroll
    for (int i = 0; i < FM; ++i) {
        #pragma unroll
        for (int j = 0; j < FN; ++j) {
            #pragma unroll
            for (int q = 0; q < 4; ++q) {
                int m = row0 + wr * (BM / 2) + i * 16 + kq * 4 + q;
                int n = col0 + wc * (BN / 2) + j * 16 + l15;
                float v = acc[i][j][q];
                if (MODE == 0) {
                    C[(size_t)m * N + n] = v + bias0[n] + bias1[n];
                } else {
                    if (n < N) {
                        int t = m >> 7, b = m & 127;
                        C[(size_t)b * (Tt * Vv) + (size_t)t * Vv + n] = v + bias0[n];
                    }
                }
            }
        }
    }
}

// ---------------------------------------------------------------------------
// Persistent LSTM recurrence, v8: 256 WGs (all 256 CUs), split-K waves.
//
// v5/v6/v7 all ~7.7-8.4 us/step despite sync/store/ordering changes =>
// binding constraint is the h broadcast: 128KB/WG/step of L3 lines,
// per-CU MLP-limited (~1024 lines @ ~700cy, ~64 in flight => ~4.6us).
// v8 halves per-CU lines by using 256 CUs:
//  - 4 cohorts (wg_m = w&3) x 64 WGs. WG: rows [wg_m*32,+32),
//    hcols [wg_n*16,+16). W_hh slice unchanged (64 gate-cols x K): 128KB LDS.
//  - 4 waves SPLIT K (quarter each, 256): no intra-WG h duplication.
//    Gather: 16 b128/thread = 64KB/WG/step (half of v5's 128KB).
//    MFMA: 64/wave/step (half). xg: 8KB/WG/step (half).
//  - Wave partials reduced via 24KB LDS (lane-major, conflict-free;
//    each wave OWNS 2 (mb,q) combos, keeps own partials in regs, writes
//    the 6 others; all register indices compile-time per wave branch).
//  - cohort = w&3: round-robin XCD dispatch puts each cohort on 2 XCDs
//    => 32 consumers share each h line in local L2 (MSHR merge).
//  - Sync: v7's proven counter tree (8 monotonic counters/cohort).
//  - hsb back to row-major [t][128][1024] (v5 layout; store granularity
//    proven irrelevant in v7).
// LDS: 131072 (W) + 24576 (redsum) = 155648 <= 160K => 1 WG/CU, 256 CUs.
// ---------------------------------------------------------------------------
__global__ __launch_bounds__(256)
void lstm_persist(const unsigned short* __restrict__ whhb, // [4096][1024] bf16
                  const float* __restrict__ xg,            // [64*128][4096] f32
                  unsigned short* __restrict__ hsb,        // [64][128][1024] bf16
                  unsigned* __restrict__ flags) {          // 32 ctrs, 64B stride
    __shared__ unsigned short Wlds[64 * Hh];        // 128 KB
    __shared__ float redsum[8 * 3 * 4 * 64];        // 24 KB  [c][slot][nb][lane]
    const int tid  = threadIdx.x;
    const int w    = blockIdx.x;
    const int wg_m = w & 3;        // row cohort: rows [wg_m*32, +32)
    const int wg_n = w >> 2;       // hcol slice (0..63)
    const int wave = tid >> 6;
    const int lane = tid & 63;
    const int l15  = lane & 15;
    const int kq   = lane >> 4;

    // preload W_hh slice: gc = gate*16+c -> global row gate*1024 + wg_n*16 + c
    for (int i = 0; i < 32; ++i) {
        int e8 = i * 256 + tid;
        int q = e8 >> 6, gc = e8 & 63;
        int grow = (gc >> 4) * Hh + wg_n * 16 + (gc & 15);
        short8 v = *reinterpret_cast<const short8*>(
            whhb + (size_t)grow * Hh + q * 8);
        *reinterpret_cast<short8*>(&Wlds[(q * 64 + gc) * 8]) = v;
    }
    __syncthreads();

    const int row0 = wg_m * 32;
    const int hcol = wg_n * 16 + l15;
    // owned output rows (local): combo cA=2*wave -> (mb=wave>>1, q=(2w)&3)
    const int lrA = (wave >> 1) * 16 + kq * 4 + ((wave & 1) * 2);
    const int lrB = lrA + 1;
    unsigned* myctr = flags + (size_t)(wg_m * 8 + (wg_n >> 3)) * 16;
    float cell0 = 0.f, cell1 = 0.f;

    float xa[2][4], xb[2][4];
    {
        const float* xrA = xg + (size_t)(row0 + lrA) * G + wg_n * 16 + l15;
        #pragma unroll
        for (int nb = 0; nb < 4; ++nb) {
            xa[0][nb] = xrA[nb * Hh];
            xa[1][nb] = xrA[G + nb * Hh];
        }
    }

#define WRC(W_, C_)                                                            \
    if (((C_) >> 1) != (W_)) {                                                 \
        _Pragma("unroll")                                                      \
        for (int nb = 0; nb < 4; ++nb)                                         \
            redsum[((C_) * 3 + (((W_) > ((C_) >> 1)) ? (W_)-1 : (W_))) * 256   \
                   + nb * 64 + lane] = acc[(C_) >> 2][nb][(C_) & 3];           \
    }

#define SPILL(W_)                                                              \
    do {                                                                       \
        _Pragma("unroll")                                                      \
        for (int nb = 0; nb < 4; ++nb) {                                       \
            own0[nb] = acc[(2 * (W_)) >> 2][nb][(2 * (W_)) & 3];               \
            own1[nb] = acc[(2 * (W_) + 1) >> 2][nb][(2 * (W_) + 1) & 3];       \
        }                                                                      \
        WRC(W_, 0); WRC(W_, 1); WRC(W_, 2); WRC(W_, 3);                        \
        WRC(W_, 4); WRC(W_, 5); WRC(W_, 6); WRC(W_, 7);                        \
    } while (0)

#define LSTM_STEP(T, XC, XN)                                                   \
    do {                                                                       \
        const int t_ = (T);                                                    \
        floatx4 acc[2][4];                                                     \
        _Pragma("unroll")                                                      \
        for (int i = 0; i < 2; ++i)                                            \
            _Pragma("unroll")                                                  \
            for (int j = 0; j < 4; ++j) acc[i][j] = (floatx4)0.f;              \
        if (t_ > 0) {                                                          \
            if (tid < 8) {                                                     \
                const unsigned* fl = flags + (size_t)(wg_m * 8 + tid) * 16;    \
                unsigned need = 8u * (unsigned)t_;                             \
                while (__hip_atomic_load(fl, __ATOMIC_RELAXED,                 \
                                         __HIP_MEMORY_SCOPE_AGENT) < need)     \
                    __builtin_amdgcn_s_sleep(1);                               \
            }                                                                  \
            __syncthreads();                                                   \
            asm volatile("" ::: "memory");                                     \
            const unsigned short* hprev = hsb + (size_t)(t_ - 1) * (Bb * Hh);  \
            const short8* ar0 = reinterpret_cast<const short8*>(               \
                hprev + (size_t)(row0 + l15) * Hh) + wave * 32 + kq;           \
            const short8* ar1 = reinterpret_cast<const short8*>(               \
                hprev + (size_t)(row0 + 16 + l15) * Hh) + wave * 32 + kq;      \
            short8 a0[8], a1[8];                                               \
            _Pragma("unroll")                                                  \
            for (int ks = 0; ks < 8; ++ks) a0[ks] = ar0[ks * 4];               \
            _Pragma("unroll")                                                  \
            for (int ks = 0; ks < 8; ++ks) a1[ks] = ar1[ks * 4];               \
            _Pragma("unroll")                                                  \
            for (int ks = 0; ks < 8; ++ks) {                                   \
                const short8* bp = reinterpret_cast<const short8*>(            \
                    &Wlds[((wave * 32 + ks * 4 + kq) * 64 + l15) * 8]);        \
                acc[0][0] = __builtin_amdgcn_mfma_f32_16x16x32_bf16(           \
                    a0[ks], bp[0], acc[0][0], 0, 0, 0);                        \
                acc[0][1] = __builtin_amdgcn_mfma_f32_16x16x32_bf16(           \
                    a0[ks], bp[16], acc[0][1], 0, 0, 0);                       \
                acc[0][2] = __builtin_amdgcn_mfma_f32_16x16x32_bf16(           \
                    a0[ks], bp[32], acc[0][2], 0, 0, 0);                       \
                acc[0][3] = __builtin_amdgcn_mfma_f32_16x16x32_bf16(           \
                    a0[ks], bp[48], acc[0][3], 0, 0, 0);                       \
            }                                                                  \
            _Pragma("unroll")                                                  \
            for (int ks = 0; ks < 8; ++ks) {                                   \
                const short8* bp = reinterpret_cast<const short8*>(            \
                    &Wlds[((wave * 32 + ks * 4 + kq) * 64 + l15) * 8]);        \
                acc[1][0] = __builtin_amdgcn_mfma_f32_16x16x32_bf16(           \
                    a1[ks], bp[0], acc[1][0], 0, 0, 0);                        \
                acc[1][1] = __builtin_amdgcn_mfma_f32_16x16x32_bf16(           \
                    a1[ks], bp[16], acc[1][1], 0, 0, 0);                       \
                acc[1][2] = __builtin_amdgcn_mfma_f32_16x16x32_bf16(           \
                    a1[ks], bp[32], acc[1][2], 0, 0, 0);                       \
                acc[1][3] = __builtin_amdgcn_mfma_f32_16x16x32_bf16(           \
                    a1[ks], bp[48], acc[1][3], 0, 0, 0);                       \
            }                                                                  \
        }                                                                      \
        float own0[4], own1[4];                                                \
        if (wave == 0)      SPILL(0);                                          \
        else if (wave == 1) SPILL(1);                                          \
        else if (wave == 2) SPILL(2);                                          \
        else                SPILL(3);                                          \
        __syncthreads();                                                       \
        float gA[4], gB[4];                                                    \
        {                                                                      \
            const int cA = wave * 2;                                           \
            _Pragma("unroll")                                                  \
            for (int nb = 0; nb < 4; ++nb) {                                   \
                int bA = (cA * 3) * 256 + nb * 64 + lane;                      \
                gA[nb] = own0[nb] + redsum[bA] + redsum[bA + 256]              \
                       + redsum[bA + 512] + XC[0][nb];                         \
                int bB = ((cA + 1) * 3) * 256 + nb * 64 + lane;                \
                gB[nb] = own1[nb] + redsum[bB] + redsum[bB + 256]              \
                       + redsum[bB + 512] + XC[1][nb];                         \
            }                                                                  \
        }                                                                      \
        unsigned short* ht = hsb + (size_t)t_ * (Bb * Hh);                     \
        {                                                                      \
            float si = sigmoid_fast(gA[0]);                                    \
            float sf = sigmoid_fast(gA[1]);                                    \
            float tg = tanh_fast(gA[2]);                                       \
            float so = sigmoid_fast(gA[3]);                                    \
            float cn = sf * cell0 + si * tg;                                   \
            cell0 = cn;                                                        \
            float h = so * tanh_fast(cn);                                      \
            __hip_atomic_store(&ht[(size_t)(row0 + lrA) * Hh + hcol], f2bf(h), \
                               __ATOMIC_RELAXED, __HIP_MEMORY_SCOPE_AGENT);    \
        }                                                                      \
        {                                                                      \
            float si = sigmoid_fast(gB[0]);                                    \
            float sf = sigmoid_fast(gB[1]);                                    \
            float tg = tanh_fast(gB[2]);                                       \
            float so = sigmoid_fast(gB[3]);                                    \
            float cn = sf * cell1 + si * tg;                                   \
            cell1 = cn;                                                        \
            float h = so * tanh_fast(cn);                                      \
            __hip_atomic_store(&ht[(size_t)(row0 + lrB) * Hh + hcol], f2bf(h), \
                               __ATOMIC_RELAXED, __HIP_MEMORY_SCOPE_AGENT);    \
        }                                                                      \
        __builtin_amdgcn_sched_barrier(0);                                     \
        if (t_ + 1 < Tt) {   /* xg prefetch: YOUNGEST VMEM (after stores) */   \
            const float* xrA = xg + (size_t)(t_ + 1) * (Bb * G)                \
                + (size_t)(row0 + lrA) * G + wg_n * 16 + l15;                  \
            _Pragma("unroll")                                                  \
            for (int nb = 0; nb < 4; ++nb) {                                   \
                XN[0][nb] = xrA[nb * Hh];                                      \
                XN[1][nb] = xrA[G + nb * Hh];                                  \
            }                                                                  \
        }                                                                      \
        __builtin_amdgcn_sched_barrier(0);                                     \
        if (t_ < Tt - 1) {                                                     \
            /* 2 h stores (oldest) + 8 xg loads outstanding: wait stores */    \
            asm volatile("s_waitcnt vmcnt(8)" ::: "memory");                   \
            __builtin_amdgcn_sched_barrier(0);                                 \
            __builtin_amdgcn_s_barrier();                                      \
            __builtin_amdgcn_sched_barrier(0);                                 \
            if (tid == 0)                                                      \
                __hip_atomic_fetch_add(myctr, 1u, __ATOMIC_RELAXED,            \
                                       __HIP_MEMORY_SCOPE_AGENT);              \
        }                                                                      \
    } while (0)

    for (int tt = 0; tt < Tt; tt += 2) {
        LSTM_STEP(tt,     xa, xb);
        LSTM_STEP(tt + 1, xb, xa);
    }
#undef LSTM_STEP
#undef SPILL
#undef WRC
}

// ---------------------------------------------------------------------------
extern "C" void kernel_launch(void* const* d_in, const int* in_sizes, int n_in,
                              void* d_out, int out_size, void* d_ws, size_t ws_size,
                              hipStream_t stream) {
    const float* features = (const float*)d_in[0];
    const int*   captions = (const int*)d_in[1];
    const float* embed_W  = (const float*)d_in[2];
    const float* W_ih     = (const float*)d_in[3];
    const float* W_hh     = (const float*)d_in[4];
    const float* b_ih     = (const float*)d_in[5];
    const float* b_hh     = (const float*)d_in[6];
    const float* fc_W     = (const float*)d_in[7];
    const float* fc_b     = (const float*)d_in[8];
    float* out = (float*)d_out;

    unsigned short* xsb  = (unsigned short*)d_ws;          // [8192][512]
    unsigned short* wihb = xsb  + (size_t)Tt * Bb * Ee;    // [4096][512]
    unsigned short* whhb = wihb + (size_t)G * Ee;          // [4096][1024]
    unsigned short* fcwb = whhb + (size_t)G * Hh;          // [10112][1024]
    unsigned short* hsb  = fcwb + (size_t)Vpad * Hh;       // [64][128][1024]
    float* xg = (float*)(hsb + (size_t)Tt * Bb * Hh);      // [8192][4096]
    unsigned* flags = (unsigned*)(xg + (size_t)Tt * Bb * G); // 32 ctrs, 64B stride

    hipMemsetAsync(flags, 0, 128 * 32 * sizeof(unsigned), stream);

    // 1) weight conversions + input gather
    cvt_bf16<<<(G * Ee / 8) / 256, 256, 0, stream>>>(W_ih, wihb, G * Ee, G * Ee);
    cvt_bf16<<<(G * Hh / 8) / 256, 256, 0, stream>>>(W_hh, whhb, G * Hh, G * Hh);
    cvt_bf16<<<(Vpad * Hh / 8) / 256, 256, 0, stream>>>(fc_W, fcwb, Vv * Hh, Vpad * Hh);
    gather_xs<<<(Tt * Bb * (Ee / 8)) / 256, 256, 0, stream>>>(
        features, captions, embed_W, xsb);

    // 2) x_gates = xs @ W_ih^T + b_ih + b_hh   (M=8192, N=4096, K=512)
    {
        dim3 grid(8192 / 128, G / 128);   // 2048 wgs (%8 == 0)
        mfma_gemm<128, 128, 0><<<grid, 256, 0, stream>>>(
            xsb, wihb, 8192, G, Ee, b_ih, b_hh, xg);
    }

    // 3) persistent LSTM recurrence (one launch, 64 steps, all 256 CUs)
    lstm_persist<<<256, 256, 0, stream>>>(whhb, xg, hsb, flags);

    // 4) out[b,t,v] = hs @ fc_W^T + fc_b   (M=8192, N=10000(pad 10112), K=1024)
    {
        dim3 grid(8192 / 128, Vpad / 128);  // 5056 wgs (%8 == 0)
        mfma_gemm<128, 128, 2><<<grid, 256, 0, stream>>>(
            hsb, fcwb, 8192, Vv, Hh, fc_b, nullptr, out);
    }
}

// Round 6
// 692.201 us; speedup vs baseline: 1.3513x; 1.0851x over previous
//
#include <hip/hip_runtime.h>
#include <math.h>

// Problem constants
static constexpr int Bb = 128;    // batch
static constexpr int Tt = 64;     // seq len
static constexpr int Ee = 512;    // embed dim
static constexpr int Hh = 1024;   // hidden
static constexpr int Vv = 10000;  // vocab
static constexpr int G  = 4 * Hh; // 4096 gates
static constexpr int Vpad = 10240; // 40*256, zero-padded vocab rows (256-tiles)

typedef __attribute__((ext_vector_type(8))) short short8;
typedef __attribute__((ext_vector_type(4))) float floatx4;

__device__ __forceinline__ unsigned short f2bf(float f) {
    unsigned u = __float_as_uint(f);
    return (unsigned short)((u + 0x7fffu + ((u >> 16) & 1u)) >> 16);  // RNE
}

__device__ __forceinline__ void gload16(const void* g, void* l) {
    __builtin_amdgcn_global_load_lds(
        (const __attribute__((address_space(1))) void*)g,
        (__attribute__((address_space(3))) void*)l, 16, 0, 0);
}

// fast transcendentals (v_exp_f32 + v_rcp_f32; ~1e-6 rel err, far below bf16)
__device__ __forceinline__ float sigmoid_fast(float x) {
    return __builtin_amdgcn_rcpf(1.f + __expf(-x));
}
__device__ __forceinline__ float tanh_fast(float x) {
    float e = __expf(-2.f * fabsf(x));
    float t = (1.f - e) * __builtin_amdgcn_rcpf(1.f + e);
    return copysignf(t, x);
}

// ---------------------------------------------------------------------------
// f32 -> bf16 convert, with zero-padding up to npad elements
// ---------------------------------------------------------------------------
__global__ __launch_bounds__(256)
void cvt_bf16(const float* __restrict__ s, unsigned short* __restrict__ d,
              int n, int npad) {
    int i8 = (blockIdx.x * 256 + threadIdx.x) * 8;
    if (i8 >= npad) return;
    short8 v;
    #pragma unroll
    for (int j = 0; j < 8; ++j) {
        int e = i8 + j;
        float f = (e < n) ? s[e] : 0.f;
        v[j] = (short)f2bf(f);
    }
    *reinterpret_cast<short8*>(d + i8) = v;
}

// ---------------------------------------------------------------------------
// Gather xs[t*B+b, :] = bf16( t==0 ? features[b,:] : embed_W[captions[b,t],:] )
// ---------------------------------------------------------------------------
__global__ __launch_bounds__(256)
void gather_xs(const float* __restrict__ features,
               const int* __restrict__ captions,
               const float* __restrict__ embed_W,
               unsigned short* __restrict__ xs) {
    int idx = blockIdx.x * 256 + threadIdx.x;   // T*B*(E/8)
    int m  = idx >> 6;                          // row, E/8 = 64 chunks per row
    int c8 = (idx & 63) * 8;
    int t = m >> 7;                             // m / B
    int b = m & 127;                            // m % B
    const float* src;
    if (t == 0) {
        src = features + (size_t)b * Ee + c8;
    } else {
        int tok = captions[(size_t)b * Tt + t];
        src = embed_W + (size_t)tok * Ee + c8;
    }
    short8 v;
    #pragma unroll
    for (int j = 0; j < 8; ++j) v[j] = (short)f2bf(src[j]);
    *reinterpret_cast<short8*>(xs + (size_t)m * Ee + c8) = v;
}

// ---------------------------------------------------------------------------
// 256x256-tile bf16 MFMA GEMM, BK=32, 4-deep circular LDS pipeline.
//   C[M,N] = A[M,K] * Bm[N,K]^T (+ epilogue per MODE)
//   MODE 0: C = A*B^T + bias0[n] + bias1[n]
//   MODE 2: out[b,t,v] = A*B^T + bias0[v], m = t*B+b, guard n < N
//
// Structure (T2+T3+T4+T5, made race-safe via 4-deep circular buffer):
//  - 8 waves (2M x 4N), per-wave output 128x64, acc[8][4] fp32x4 (128 VGPR).
//  - LDS = 4 K-tile buffers x (A 256x32 + B 256x32) bf16 = 128 KB.
//    Tile tau lives in buf[tau&3]; stages for tau+2 issued during tau's
//    phases -> target buffer last read at tile tau-2, >=4 barriers earlier.
//  - 2 phases per K-tile: {ds_read frags | stage 2 half-tiles | s_barrier |
//    setprio(1) 16 MFMA setprio(0) | s_barrier}.
//  - counted vmcnt(4) once per tile (t+2's 4 loads stay in flight), never 0
//    in steady state; raw s_barrier (NOT __syncthreads -> no vmcnt drain).
//  - LDS XOR swizzle byte ^= ((row&3)<<4), both-sides: pre-swizzled GLOBAL
//    source (gload_lds dest stays linear) + swizzled ds_read address.
//  - XCD-aware bijective grid swizzle (nwg % 8 == 0).
// ---------------------------------------------------------------------------
__device__ __forceinline__ void stage_half(
    const unsigned short* __restrict__ Gsrc, int Kdim, int rowbase, int k0,
    unsigned short* ldsbase, int tid) {
    // one 16B load per thread covers the 8 KB half-tile (128 rows x 32 k)
    int e = tid * 16;                     // byte offset in half-tile
    int r = e >> 6;                       // row 0..127
    int c = e & 63;                       // byte in row (0/16/32/48)
    int c_log = c ^ ((r & 3) << 4);       // inverse-swizzled source column
    gload16(Gsrc + (size_t)(rowbase + r) * Kdim + k0 + (c_log >> 1),
            ldsbase + tid * 8);
}

template<int MODE>
__global__ __launch_bounds__(512, 2)
void gemm256(const unsigned short* __restrict__ A,
             const unsigned short* __restrict__ Bm,
             int M, int N, int K,
             const float* __restrict__ bias0, const float* __restrict__ bias1,
             float* __restrict__ C) {
    constexpr int BK = 32;
    __shared__ unsigned short lds[4 * 2 * 256 * BK];   // 128 KB

    const int nwg = gridDim.x * gridDim.y;
    const int flat = blockIdx.y * gridDim.x + blockIdx.x;
    const int tix = (flat & 7) * (nwg >> 3) + (flat >> 3);
    const int bx = tix % gridDim.x;
    const int by = tix / gridDim.x;

    const int tid  = threadIdx.x;
    const int wid  = tid >> 6;      // 0..7
    const int lane = tid & 63;
    const int wm = wid >> 2;        // 0..1  (M half)
    const int wn = wid & 3;         // 0..3  (N quarter)
    const int row0 = bx * 256;
    const int col0 = by * 256;
    const int l15 = lane & 15;
    const int kq  = lane >> 4;

    const int NT = K / BK;

    // per-thread ds_read bases (shorts); swizzled slot kq ^ (row&3), row&3==l15&3
    const int swz = (kq ^ (l15 & 3)) * 8;
    const int arow_s = wm * 4096 + l15 * 32 + swz;
    const int brow_s = 8192 + (wn >> 1) * 4096 + ((wn & 1) * 64 + l15) * 32 + swz;

    floatx4 acc[8][4];
    #pragma unroll
    for (int i = 0; i < 8; ++i)
        #pragma unroll
        for (int j = 0; j < 4; ++j) acc[i][j] = (floatx4)0.f;

    // prologue: stage tiles 0 and 1 (4 half-tiles each)
    stage_half(A,  K, row0,       0,  &lds[0],     tid);
    stage_half(A,  K, row0 + 128, 0,  &lds[4096],  tid);
    stage_half(Bm, K, col0,       0,  &lds[8192],  tid);
    stage_half(Bm, K, col0 + 128, 0,  &lds[12288], tid);
    stage_half(A,  K, row0,       BK, &lds[16384 + 0],     tid);
    stage_half(A,  K, row0 + 128, BK, &lds[16384 + 4096],  tid);
    stage_half(Bm, K, col0,       BK, &lds[16384 + 8192],  tid);
    stage_half(Bm, K, col0 + 128, BK, &lds[16384 + 12288], tid);
    asm volatile("s_waitcnt vmcnt(4)" ::: "memory");   // tile 0 landed
    asm volatile("s_barrier" ::: "memory");

    for (int t = 0; t < NT; ++t) {
        const int cur = (t & 3) * 16384;
        short8 af[4], bfr[4];
        // ---- phase A: A frags fi 0-3 + all B frags; stage A halves of t+2 ----
        #pragma unroll
        for (int fi = 0; fi < 4; ++fi)
            af[fi] = *reinterpret_cast<const short8*>(&lds[cur + arow_s + fi * 512]);
        #pragma unroll
        for (int fj = 0; fj < 4; ++fj)
            bfr[fj] = *reinterpret_cast<const short8*>(&lds[cur + brow_s + fj * 512]);
        if (t + 2 < NT) {
            const int nb = ((t + 2) & 3) * 16384;
            stage_half(A, K, row0,       (t + 2) * BK, &lds[nb],        tid);
            stage_half(A, K, row0 + 128, (t + 2) * BK, &lds[nb + 4096], tid);
        }
        asm volatile("s_barrier" ::: "memory");
        __builtin_amdgcn_s_setprio(1);
        #pragma unroll
        for (int fi = 0; fi < 4; ++fi)
            #pragma unroll
            for (int fj = 0; fj < 4; ++fj)
                acc[fi][fj] = __builtin_amdgcn_mfma_f32_16x16x32_bf16(
                    af[fi], bfr[fj], acc[fi][fj], 0, 0, 0);
        __builtin_amdgcn_s_setprio(0);
        asm volatile("s_barrier" ::: "memory");
        // ---- phase B: A frags fi 4-7; stage B halves of t+2 ----
        #pragma unroll
        for (int fi = 0; fi < 4; ++fi)
            af[fi] = *reinterpret_cast<const short8*>(
                &lds[cur + arow_s + (fi + 4) * 512]);
        if (t + 2 < NT) {
            const int nb = ((t + 2) & 3) * 16384 + 8192;
            stage_half(Bm, K, col0,       (t + 2) * BK, &lds[nb],        tid);
            stage_half(Bm, K, col0 + 128, (t + 2) * BK, &lds[nb + 4096], tid);
        }
        asm volatile("s_barrier" ::: "memory");
        __builtin_amdgcn_s_setprio(1);
        #pragma unroll
        for (int fi = 0; fi < 4; ++fi)
            #pragma unroll
            for (int fj = 0; fj < 4; ++fj)
                acc[fi + 4][fj] = __builtin_amdgcn_mfma_f32_16x16x32_bf16(
                    af[fi], bfr[fj], acc[fi + 4][fj], 0, 0, 0);
        __builtin_amdgcn_s_setprio(0);
        if (t + 1 < NT) {
            // gate tile t+1's data: only t+2's 4 stage-loads may stay in flight
            if (t + 2 < NT) asm volatile("s_waitcnt vmcnt(4)" ::: "memory");
            else            asm volatile("s_waitcnt vmcnt(0)" ::: "memory");
        }
        asm volatile("s_barrier" ::: "memory");
    }

    // epilogue
    #pragma unroll
    for (int fi = 0; fi < 8; ++fi) {
        #pragma unroll
        for (int fj = 0; fj < 4; ++fj) {
            #pragma unroll
            for (int q = 0; q < 4; ++q) {
                int m = row0 + wm * 128 + fi * 16 + kq * 4 + q;
                int n = col0 + wn * 64 + fj * 16 + l15;
                float v = acc[fi][fj][q];
                if (MODE == 0) {
                    C[(size_t)m * N + n] = v + bias0[n] + bias1[n];
                } else {
                    if (n < N) {
                        int t = m >> 7, b = m & 127;
                        C[(size_t)b * (Tt * Vv) + (size_t)t * Vv + n] = v + bias0[n];
                    }
                }
            }
        }
    }
}

// ---------------------------------------------------------------------------
// Persistent LSTM recurrence, v8 (proven 362 us, passing).
// 256 WGs (all 256 CUs), split-K waves, counter-tree sync.
// ---------------------------------------------------------------------------
__global__ __launch_bounds__(256)
void lstm_persist(const unsigned short* __restrict__ whhb, // [4096][1024] bf16
                  const float* __restrict__ xg,            // [64*128][4096] f32
                  unsigned short* __restrict__ hsb,        // [64][128][1024] bf16
                  unsigned* __restrict__ flags) {          // 32 ctrs, 64B stride
    __shared__ unsigned short Wlds[64 * Hh];        // 128 KB
    __shared__ float redsum[8 * 3 * 4 * 64];        // 24 KB  [c][slot][nb][lane]
    const int tid  = threadIdx.x;
    const int w    = blockIdx.x;
    const int wg_m = w & 3;        // row cohort: rows [wg_m*32, +32)
    const int wg_n = w >> 2;       // hcol slice (0..63)
    const int wave = tid >> 6;
    const int lane = tid & 63;
    const int l15  = lane & 15;
    const int kq   = lane >> 4;

    for (int i = 0; i < 32; ++i) {
        int e8 = i * 256 + tid;
        int q = e8 >> 6, gc = e8 & 63;
        int grow = (gc >> 4) * Hh + wg_n * 16 + (gc & 15);
        short8 v = *reinterpret_cast<const short8*>(
            whhb + (size_t)grow * Hh + q * 8);
        *reinterpret_cast<short8*>(&Wlds[(q * 64 + gc) * 8]) = v;
    }
    __syncthreads();

    const int row0 = wg_m * 32;
    const int hcol = wg_n * 16 + l15;
    const int lrA = (wave >> 1) * 16 + kq * 4 + ((wave & 1) * 2);
    const int lrB = lrA + 1;
    unsigned* myctr = flags + (size_t)(wg_m * 8 + (wg_n >> 3)) * 16;
    float cell0 = 0.f, cell1 = 0.f;

    float xa[2][4], xb[2][4];
    {
        const float* xrA = xg + (size_t)(row0 + lrA) * G + wg_n * 16 + l15;
        #pragma unroll
        for (int nb = 0; nb < 4; ++nb) {
            xa[0][nb] = xrA[nb * Hh];
            xa[1][nb] = xrA[G + nb * Hh];
        }
    }

#define WRC(W_, C_)                                                            \
    if (((C_) >> 1) != (W_)) {                                                 \
        _Pragma("unroll")                                                      \
        for (int nb = 0; nb < 4; ++nb)                                         \
            redsum[((C_) * 3 + (((W_) > ((C_) >> 1)) ? (W_)-1 : (W_))) * 256   \
                   + nb * 64 + lane] = acc[(C_) >> 2][nb][(C_) & 3];           \
    }

#define SPILL(W_)                                                              \
    do {                                                                       \
        _Pragma("unroll")                                                      \
        for (int nb = 0; nb < 4; ++nb) {                                       \
            own0[nb] = acc[(2 * (W_)) >> 2][nb][(2 * (W_)) & 3];               \
            own1[nb] = acc[(2 * (W_) + 1) >> 2][nb][(2 * (W_) + 1) & 3];       \
        }                                                                      \
        WRC(W_, 0); WRC(W_, 1); WRC(W_, 2); WRC(W_, 3);                        \
        WRC(W_, 4); WRC(W_, 5); WRC(W_, 6); WRC(W_, 7);                        \
    } while (0)

#define LSTM_STEP(T, XC, XN)                                                   \
    do {                                                                       \
        const int t_ = (T);                                                    \
        floatx4 acc[2][4];                                                     \
        _Pragma("unroll")                                                      \
        for (int i = 0; i < 2; ++i)                                            \
            _Pragma("unroll")                                                  \
            for (int j = 0; j < 4; ++j) acc[i][j] = (floatx4)0.f;              \
        if (t_ > 0) {                                                          \
            if (tid < 8) {                                                     \
                const unsigned* fl = flags + (size_t)(wg_m * 8 + tid) * 16;    \
                unsigned need = 8u * (unsigned)t_;                             \
                while (__hip_atomic_load(fl, __ATOMIC_RELAXED,                 \
                                         __HIP_MEMORY_SCOPE_AGENT) < need)     \
                    __builtin_amdgcn_s_sleep(1);                               \
            }                                                                  \
            __syncthreads();                                                   \
            asm volatile("" ::: "memory");                                     \
            const unsigned short* hprev = hsb + (size_t)(t_ - 1) * (Bb * Hh);  \
            const short8* ar0 = reinterpret_cast<const short8*>(               \
                hprev + (size_t)(row0 + l15) * Hh) + wave * 32 + kq;           \
            const short8* ar1 = reinterpret_cast<const short8*>(               \
                hprev + (size_t)(row0 + 16 + l15) * Hh) + wave * 32 + kq;      \
            short8 a0[8], a1[8];                                               \
            _Pragma("unroll")                                                  \
            for (int ks = 0; ks < 8; ++ks) a0[ks] = ar0[ks * 4];               \
            _Pragma("unroll")                                                  \
            for (int ks = 0; ks < 8; ++ks) a1[ks] = ar1[ks * 4];               \
            _Pragma("unroll")                                                  \
            for (int ks = 0; ks < 8; ++ks) {                                   \
                const short8* bp = reinterpret_cast<const short8*>(            \
                    &Wlds[((wave * 32 + ks * 4 + kq) * 64 + l15) * 8]);        \
                acc[0][0] = __builtin_amdgcn_mfma_f32_16x16x32_bf16(           \
                    a0[ks], bp[0], acc[0][0], 0, 0, 0);                        \
                acc[0][1] = __builtin_amdgcn_mfma_f32_16x16x32_bf16(           \
                    a0[ks], bp[16], acc[0][1], 0, 0, 0);                       \
                acc[0][2] = __builtin_amdgcn_mfma_f32_16x16x32_bf16(           \
                    a0[ks], bp[32], acc[0][2], 0, 0, 0);                       \
                acc[0][3] = __builtin_amdgcn_mfma_f32_16x16x32_bf16(           \
                    a0[ks], bp[48], acc[0][3], 0, 0, 0);                       \
            }                                                                  \
            _Pragma("unroll")                                                  \
            for (int ks = 0; ks < 8; ++ks) {                                   \
                const short8* bp = reinterpret_cast<const short8*>(            \
                    &Wlds[((wave * 32 + ks * 4 + kq) * 64 + l15) * 8]);        \
                acc[1][0] = __builtin_amdgcn_mfma_f32_16x16x32_bf16(           \
                    a1[ks], bp[0], acc[1][0], 0, 0, 0);                        \
                acc[1][1] = __builtin_amdgcn_mfma_f32_16x16x32_bf16(           \
                    a1[ks], bp[16], acc[1][1], 0, 0, 0);                       \
                acc[1][2] = __builtin_amdgcn_mfma_f32_16x16x32_bf16(           \
                    a1[ks], bp[32], acc[1][2], 0, 0, 0);                       \
                acc[1][3] = __builtin_amdgcn_mfma_f32_16x16x32_bf16(           \
                    a1[ks], bp[48], acc[1][3], 0, 0, 0);                       \
            }                                                                  \
        }                                                                      \
        float own0[4], own1[4];                                                \
        if (wave == 0)      SPILL(0);                                          \
        else if (wave == 1) SPILL(1);                                          \
        else if (wave == 2) SPILL(2);                                          \
        else                SPILL(3);                                          \
        __syncthreads();                                                       \
        float gA[4], gB[4];                                                    \
        {                                                                      \
            const int cA = wave * 2;                                           \
            _Pragma("unroll")                                                  \
            for (int nb = 0; nb < 4; ++nb) {                                   \
                int bA = (cA * 3) * 256 + nb * 64 + lane;                      \
                gA[nb] = own0[nb] + redsum[bA] + redsum[bA + 256]              \
                       + redsum[bA + 512] + XC[0][nb];                         \
                int bB = ((cA + 1) * 3) * 256 + nb * 64 + lane;                \
                gB[nb] = own1[nb] + redsum[bB] + redsum[bB + 256]              \
                       + redsum[bB + 512] + XC[1][nb];                         \
            }                                                                  \
        }                                                                      \
        unsigned short* ht = hsb + (size_t)t_ * (Bb * Hh);                     \
        {                                                                      \
            float si = sigmoid_fast(gA[0]);                                    \
            float sf = sigmoid_fast(gA[1]);                                    \
            float tg = tanh_fast(gA[2]);                                       \
            float so = sigmoid_fast(gA[3]);                                    \
            float cn = sf * cell0 + si * tg;                                   \
            cell0 = cn;                                                        \
            float h = so * tanh_fast(cn);                                      \
            __hip_atomic_store(&ht[(size_t)(row0 + lrA) * Hh + hcol], f2bf(h), \
                               __ATOMIC_RELAXED, __HIP_MEMORY_SCOPE_AGENT);    \
        }                                                                      \
        {                                                                      \
            float si = sigmoid_fast(gB[0]);                                    \
            float sf = sigmoid_fast(gB[1]);                                    \
            float tg = tanh_fast(gB[2]);                                       \
            float so = sigmoid_fast(gB[3]);                                    \
            float cn = sf * cell1 + si * tg;                                   \
            cell1 = cn;                                                        \
            float h = so * tanh_fast(cn);                                      \
            __hip_atomic_store(&ht[(size_t)(row0 + lrB) * Hh + hcol], f2bf(h), \
                               __ATOMIC_RELAXED, __HIP_MEMORY_SCOPE_AGENT);    \
        }                                                                      \
        __builtin_amdgcn_sched_barrier(0);                                     \
        if (t_ + 1 < Tt) {   /* xg prefetch: YOUNGEST VMEM (after stores) */   \
            const float* xrA = xg + (size_t)(t_ + 1) * (Bb * G)                \
                + (size_t)(row0 + lrA) * G + wg_n * 16 + l15;                  \
            _Pragma("unroll")                                                  \
            for (int nb = 0; nb < 4; ++nb) {                                   \
                XN[0][nb] = xrA[nb * Hh];                                      \
                XN[1][nb] = xrA[G + nb * Hh];                                  \
            }                                                                  \
        }                                                                      \
        __builtin_amdgcn_sched_barrier(0);                                     \
        if (t_ < Tt - 1) {                                                     \
            /* 2 h stores (oldest) + 8 xg loads outstanding: wait stores */    \
            asm volatile("s_waitcnt vmcnt(8)" ::: "memory");                   \
            __builtin_amdgcn_sched_barrier(0);                                 \
            __builtin_amdgcn_s_barrier();                                      \
            __builtin_amdgcn_sched_barrier(0);                                 \
            if (tid == 0)                                                      \
                __hip_atomic_fetch_add(myctr, 1u, __ATOMIC_RELAXED,            \
                                       __HIP_MEMORY_SCOPE_AGENT);              \
        }                                                                      \
    } while (0)

    for (int tt = 0; tt < Tt; tt += 2) {
        LSTM_STEP(tt,     xa, xb);
        LSTM_STEP(tt + 1, xb, xa);
    }
#undef LSTM_STEP
#undef SPILL
#undef WRC
}

// ---------------------------------------------------------------------------
extern "C" void kernel_launch(void* const* d_in, const int* in_sizes, int n_in,
                              void* d_out, int out_size, void* d_ws, size_t ws_size,
                              hipStream_t stream) {
    const float* features = (const float*)d_in[0];
    const int*   captions = (const int*)d_in[1];
    const float* embed_W  = (const float*)d_in[2];
    const float* W_ih     = (const float*)d_in[3];
    const float* W_hh     = (const float*)d_in[4];
    const float* b_ih     = (const float*)d_in[5];
    const float* b_hh     = (const float*)d_in[6];
    const float* fc_W     = (const float*)d_in[7];
    const float* fc_b     = (const float*)d_in[8];
    float* out = (float*)d_out;

    unsigned short* xsb  = (unsigned short*)d_ws;          // [8192][512]
    unsigned short* wihb = xsb  + (size_t)Tt * Bb * Ee;    // [4096][512]
    unsigned short* whhb = wihb + (size_t)G * Ee;          // [4096][1024]
    unsigned short* fcwb = whhb + (size_t)G * Hh;          // [10240][1024]
    unsigned short* hsb  = fcwb + (size_t)Vpad * Hh;       // [64][128][1024]
    float* xg = (float*)(hsb + (size_t)Tt * Bb * Hh);      // [8192][4096]
    unsigned* flags = (unsigned*)(xg + (size_t)Tt * Bb * G); // 32 ctrs, 64B stride

    (void)hipMemsetAsync(flags, 0, 128 * 32 * sizeof(unsigned), stream);

    // 1) weight conversions + input gather
    cvt_bf16<<<(G * Ee / 8) / 256, 256, 0, stream>>>(W_ih, wihb, G * Ee, G * Ee);
    cvt_bf16<<<(G * Hh / 8) / 256, 256, 0, stream>>>(W_hh, whhb, G * Hh, G * Hh);
    cvt_bf16<<<(Vpad * Hh / 8) / 256, 256, 0, stream>>>(fc_W, fcwb, Vv * Hh, Vpad * Hh);
    gather_xs<<<(Tt * Bb * (Ee / 8)) / 256, 256, 0, stream>>>(
        features, captions, embed_W, xsb);

    // 2) x_gates = xs @ W_ih^T + b_ih + b_hh   (M=8192, N=4096, K=512)
    {
        dim3 grid(8192 / 256, G / 256);   // 32 x 16 = 512 wgs (%8 == 0)
        gemm256<0><<<grid, 512, 0, stream>>>(
            xsb, wihb, 8192, G, Ee, b_ih, b_hh, xg);
    }

    // 3) persistent LSTM recurrence (one launch, 64 steps, all 256 CUs)
    lstm_persist<<<256, 256, 0, stream>>>(whhb, xg, hsb, flags);

    // 4) out[b,t,v] = hs @ fc_W^T + fc_b   (M=8192, N=10000(pad 10240), K=1024)
    {
        dim3 grid(8192 / 256, Vpad / 256);  // 32 x 40 = 1280 wgs (%8 == 0)
        gemm256<2><<<grid, 512, 0, stream>>>(
            hsb, fcwb, 8192, Vv, Hh, fc_b, nullptr, out);
    }
}

// Round 7
// 673.972 us; speedup vs baseline: 1.3878x; 1.0270x over previous
//
#include <hip/hip_runtime.h>
#include <math.h>

// Problem constants
static constexpr int Bb = 128;    // batch
static constexpr int Tt = 64;     // seq len
static constexpr int Ee = 512;    // embed dim
static constexpr int Hh = 1024;   // hidden
static constexpr int Vv = 10000;  // vocab
static constexpr int G  = 4 * Hh; // 4096 gates
static constexpr int Vpad = 10240; // 40*256, zero-padded vocab rows (256-tiles)

typedef __attribute__((ext_vector_type(8))) short short8;
typedef __attribute__((ext_vector_type(4))) float floatx4;

__device__ __forceinline__ unsigned short f2bf(float f) {
    unsigned u = __float_as_uint(f);
    return (unsigned short)((u + 0x7fffu + ((u >> 16) & 1u)) >> 16);  // RNE
}

__device__ __forceinline__ void gload16(const void* g, void* l) {
    __builtin_amdgcn_global_load_lds(
        (const __attribute__((address_space(1))) void*)g,
        (__attribute__((address_space(3))) void*)l, 16, 0, 0);
}

// fast transcendentals (v_exp_f32 + v_rcp_f32; ~1e-6 rel err, far below bf16)
__device__ __forceinline__ float sigmoid_fast(float x) {
    return __builtin_amdgcn_rcpf(1.f + __expf(-x));
}
__device__ __forceinline__ float tanh_fast(float x) {
    float e = __expf(-2.f * fabsf(x));
    float t = (1.f - e) * __builtin_amdgcn_rcpf(1.f + e);
    return copysignf(t, x);
}

// ---------------------------------------------------------------------------
// f32 -> bf16 convert, with zero-padding up to npad elements
// ---------------------------------------------------------------------------
__global__ __launch_bounds__(256)
void cvt_bf16(const float* __restrict__ s, unsigned short* __restrict__ d,
              int n, int npad) {
    int i8 = (blockIdx.x * 256 + threadIdx.x) * 8;
    if (i8 >= npad) return;
    short8 v;
    #pragma unroll
    for (int j = 0; j < 8; ++j) {
        int e = i8 + j;
        float f = (e < n) ? s[e] : 0.f;
        v[j] = (short)f2bf(f);
    }
    *reinterpret_cast<short8*>(d + i8) = v;
}

// ---------------------------------------------------------------------------
// Gather xs[t*B+b, :] = bf16( t==0 ? features[b,:] : embed_W[captions[b,t],:] )
// ---------------------------------------------------------------------------
__global__ __launch_bounds__(256)
void gather_xs(const float* __restrict__ features,
               const int* __restrict__ captions,
               const float* __restrict__ embed_W,
               unsigned short* __restrict__ xs) {
    int idx = blockIdx.x * 256 + threadIdx.x;   // T*B*(E/8)
    int m  = idx >> 6;                          // row, E/8 = 64 chunks per row
    int c8 = (idx & 63) * 8;
    int t = m >> 7;                             // m / B
    int b = m & 127;                            // m % B
    const float* src;
    if (t == 0) {
        src = features + (size_t)b * Ee + c8;
    } else {
        int tok = captions[(size_t)b * Tt + t];
        src = embed_W + (size_t)tok * Ee + c8;
    }
    short8 v;
    #pragma unroll
    for (int j = 0; j < 8; ++j) v[j] = (short)f2bf(src[j]);
    *reinterpret_cast<short8*>(xs + (size_t)m * Ee + c8) = v;
}

// ---------------------------------------------------------------------------
// 256x256-tile bf16 MFMA GEMM, BK=32, 4-deep circular LDS pipeline.
//   (unchanged from v10 — proven passing at 692 us total)
// ---------------------------------------------------------------------------
__device__ __forceinline__ void stage_half(
    const unsigned short* __restrict__ Gsrc, int Kdim, int rowbase, int k0,
    unsigned short* ldsbase, int tid) {
    // one 16B load per thread covers the 8 KB half-tile (128 rows x 32 k)
    int e = tid * 16;                     // byte offset in half-tile
    int r = e >> 6;                       // row 0..127
    int c = e & 63;                       // byte in row (0/16/32/48)
    int c_log = c ^ ((r & 3) << 4);       // inverse-swizzled source column
    gload16(Gsrc + (size_t)(rowbase + r) * Kdim + k0 + (c_log >> 1),
            ldsbase + tid * 8);
}

template<int MODE>
__global__ __launch_bounds__(512, 2)
void gemm256(const unsigned short* __restrict__ A,
             const unsigned short* __restrict__ Bm,
             int M, int N, int K,
             const float* __restrict__ bias0, const float* __restrict__ bias1,
             float* __restrict__ C) {
    constexpr int BK = 32;
    __shared__ unsigned short lds[4 * 2 * 256 * BK];   // 128 KB

    const int nwg = gridDim.x * gridDim.y;
    const int flat = blockIdx.y * gridDim.x + blockIdx.x;
    const int tix = (flat & 7) * (nwg >> 3) + (flat >> 3);
    const int bx = tix % gridDim.x;
    const int by = tix / gridDim.x;

    const int tid  = threadIdx.x;
    const int wid  = tid >> 6;      // 0..7
    const int lane = tid & 63;
    const int wm = wid >> 2;        // 0..1  (M half)
    const int wn = wid & 3;         // 0..3  (N quarter)
    const int row0 = bx * 256;
    const int col0 = by * 256;
    const int l15 = lane & 15;
    const int kq  = lane >> 4;

    const int NT = K / BK;

    // per-thread ds_read bases (shorts); swizzled slot kq ^ (row&3), row&3==l15&3
    const int swz = (kq ^ (l15 & 3)) * 8;
    const int arow_s = wm * 4096 + l15 * 32 + swz;
    const int brow_s = 8192 + (wn >> 1) * 4096 + ((wn & 1) * 64 + l15) * 32 + swz;

    floatx4 acc[8][4];
    #pragma unroll
    for (int i = 0; i < 8; ++i)
        #pragma unroll
        for (int j = 0; j < 4; ++j) acc[i][j] = (floatx4)0.f;

    // prologue: stage tiles 0 and 1 (4 half-tiles each)
    stage_half(A,  K, row0,       0,  &lds[0],     tid);
    stage_half(A,  K, row0 + 128, 0,  &lds[4096],  tid);
    stage_half(Bm, K, col0,       0,  &lds[8192],  tid);
    stage_half(Bm, K, col0 + 128, 0,  &lds[12288], tid);
    stage_half(A,  K, row0,       BK, &lds[16384 + 0],     tid);
    stage_half(A,  K, row0 + 128, BK, &lds[16384 + 4096],  tid);
    stage_half(Bm, K, col0,       BK, &lds[16384 + 8192],  tid);
    stage_half(Bm, K, col0 + 128, BK, &lds[16384 + 12288], tid);
    asm volatile("s_waitcnt vmcnt(4)" ::: "memory");   // tile 0 landed
    asm volatile("s_barrier" ::: "memory");

    for (int t = 0; t < NT; ++t) {
        const int cur = (t & 3) * 16384;
        short8 af[4], bfr[4];
        // ---- phase A: A frags fi 0-3 + all B frags; stage A halves of t+2 ----
        #pragma unroll
        for (int fi = 0; fi < 4; ++fi)
            af[fi] = *reinterpret_cast<const short8*>(&lds[cur + arow_s + fi * 512]);
        #pragma unroll
        for (int fj = 0; fj < 4; ++fj)
            bfr[fj] = *reinterpret_cast<const short8*>(&lds[cur + brow_s + fj * 512]);
        if (t + 2 < NT) {
            const int nb = ((t + 2) & 3) * 16384;
            stage_half(A, K, row0,       (t + 2) * BK, &lds[nb],        tid);
            stage_half(A, K, row0 + 128, (t + 2) * BK, &lds[nb + 4096], tid);
        }
        asm volatile("s_barrier" ::: "memory");
        __builtin_amdgcn_s_setprio(1);
        #pragma unroll
        for (int fi = 0; fi < 4; ++fi)
            #pragma unroll
            for (int fj = 0; fj < 4; ++fj)
                acc[fi][fj] = __builtin_amdgcn_mfma_f32_16x16x32_bf16(
                    af[fi], bfr[fj], acc[fi][fj], 0, 0, 0);
        __builtin_amdgcn_s_setprio(0);
        asm volatile("s_barrier" ::: "memory");
        // ---- phase B: A frags fi 4-7; stage B halves of t+2 ----
        #pragma unroll
        for (int fi = 0; fi < 4; ++fi)
            af[fi] = *reinterpret_cast<const short8*>(
                &lds[cur + arow_s + (fi + 4) * 512]);
        if (t + 2 < NT) {
            const int nb = ((t + 2) & 3) * 16384 + 8192;
            stage_half(Bm, K, col0,       (t + 2) * BK, &lds[nb],        tid);
            stage_half(Bm, K, col0 + 128, (t + 2) * BK, &lds[nb + 4096], tid);
        }
        asm volatile("s_barrier" ::: "memory");
        __builtin_amdgcn_s_setprio(1);
        #pragma unroll
        for (int fi = 0; fi < 4; ++fi)
            #pragma unroll
            for (int fj = 0; fj < 4; ++fj)
                acc[fi + 4][fj] = __builtin_amdgcn_mfma_f32_16x16x32_bf16(
                    af[fi], bfr[fj], acc[fi + 4][fj], 0, 0, 0);
        __builtin_amdgcn_s_setprio(0);
        if (t + 1 < NT) {
            // gate tile t+1's data: only t+2's 4 stage-loads may stay in flight
            if (t + 2 < NT) asm volatile("s_waitcnt vmcnt(4)" ::: "memory");
            else            asm volatile("s_waitcnt vmcnt(0)" ::: "memory");
        }
        asm volatile("s_barrier" ::: "memory");
    }

    // epilogue
    #pragma unroll
    for (int fi = 0; fi < 8; ++fi) {
        #pragma unroll
        for (int fj = 0; fj < 4; ++fj) {
            #pragma unroll
            for (int q = 0; q < 4; ++q) {
                int m = row0 + wm * 128 + fi * 16 + kq * 4 + q;
                int n = col0 + wn * 64 + fj * 16 + l15;
                float v = acc[fi][fj][q];
                if (MODE == 0) {
                    C[(size_t)m * N + n] = v + bias0[n] + bias1[n];
                } else {
                    if (n < N) {
                        int t = m >> 7, b = m & 127;
                        C[(size_t)b * (Tt * Vv) + (size_t)t * Vv + n] = v + bias0[n];
                    }
                }
            }
        }
    }
}

// ---------------------------------------------------------------------------
// v11: rotated h-gather for the LSTM recurrence.
// All 32 WGs on an XCD read IDENTICAL h addresses in IDENTICAL order, so the
// XCD requests L3 lines in lockstep and the per-CU MLP window (~64 lines)
// bounds the union of outstanding distinct lines. Rotating the load+MFMA
// order per WG (compile-time ROT by (wg_n>>1)&3, which cycles 0..3 within an
// XCD under round-robin w->XCD dispatch) makes the union of first-issued
// lines cover ALL 512 cohort lines immediately: L2 fills once at t~0, later
// accesses hit L2 (~200cy vs ~700cy). ks-rotation by {0,2,4,6} shifts the
// starting 128B line by {0,1,2,3} within each wave's quarter-row. MFMA
// consumption rotated identically (static j=(ks+ROT)&7 -> W chunk j) —
// pure fp-reassociation, no data change.
// ---------------------------------------------------------------------------
template<int ROT>
__device__ __forceinline__ void gate_mfma(
    const unsigned short* __restrict__ hprev,
    const unsigned short* __restrict__ Wl,
    int row0, int wave, int l15, int kq,
    floatx4 (&acc)[2][4])
{
    const short8* ar0 = reinterpret_cast<const short8*>(
        hprev + (size_t)(row0 + l15) * Hh) + wave * 32 + kq;
    const short8* ar1 = reinterpret_cast<const short8*>(
        hprev + (size_t)(row0 + 16 + l15) * Hh) + wave * 32 + kq;
    short8 a0[8], a1[8];
    #pragma unroll
    for (int ks = 0; ks < 8; ++ks) {
        const int j = (ks + ROT) & 7;
        a0[ks] = ar0[j * 4];
        a1[ks] = ar1[j * 4];
    }
    #pragma unroll
    for (int ks = 0; ks < 8; ++ks) {
        const int j = (ks + ROT) & 7;
        const short8* bp = reinterpret_cast<const short8*>(
            &Wl[((wave * 32 + j * 4 + kq) * 64 + l15) * 8]);
        acc[0][0] = __builtin_amdgcn_mfma_f32_16x16x32_bf16(
            a0[ks], bp[0], acc[0][0], 0, 0, 0);
        acc[0][1] = __builtin_amdgcn_mfma_f32_16x16x32_bf16(
            a0[ks], bp[16], acc[0][1], 0, 0, 0);
        acc[0][2] = __builtin_amdgcn_mfma_f32_16x16x32_bf16(
            a0[ks], bp[32], acc[0][2], 0, 0, 0);
        acc[0][3] = __builtin_amdgcn_mfma_f32_16x16x32_bf16(
            a0[ks], bp[48], acc[0][3], 0, 0, 0);
    }
    #pragma unroll
    for (int ks = 0; ks < 8; ++ks) {
        const int j = (ks + ROT) & 7;
        const short8* bp = reinterpret_cast<const short8*>(
            &Wl[((wave * 32 + j * 4 + kq) * 64 + l15) * 8]);
        acc[1][0] = __builtin_amdgcn_mfma_f32_16x16x32_bf16(
            a1[ks], bp[0], acc[1][0], 0, 0, 0);
        acc[1][1] = __builtin_amdgcn_mfma_f32_16x16x32_bf16(
            a1[ks], bp[16], acc[1][1], 0, 0, 0);
        acc[1][2] = __builtin_amdgcn_mfma_f32_16x16x32_bf16(
            a1[ks], bp[32], acc[1][2], 0, 0, 0);
        acc[1][3] = __builtin_amdgcn_mfma_f32_16x16x32_bf16(
            a1[ks], bp[48], acc[1][3], 0, 0, 0);
    }
}

// ---------------------------------------------------------------------------
// Persistent LSTM recurrence (v8 structure + v11 rotated gather).
// 256 WGs (all 256 CUs), split-K waves, counter-tree sync.
// ---------------------------------------------------------------------------
__global__ __launch_bounds__(256)
void lstm_persist(const unsigned short* __restrict__ whhb, // [4096][1024] bf16
                  const float* __restrict__ xg,            // [64*128][4096] f32
                  unsigned short* __restrict__ hsb,        // [64][128][1024] bf16
                  unsigned* __restrict__ flags) {          // 32 ctrs, 64B stride
    __shared__ unsigned short Wlds[64 * Hh];        // 128 KB
    __shared__ float redsum[8 * 3 * 4 * 64];        // 24 KB  [c][slot][nb][lane]
    const int tid  = threadIdx.x;
    const int w    = blockIdx.x;
    const int wg_m = w & 3;        // row cohort: rows [wg_m*32, +32)
    const int wg_n = w >> 2;       // hcol slice (0..63)
    const int wave = tid >> 6;
    const int lane = tid & 63;
    const int l15  = lane & 15;
    const int kq   = lane >> 4;

    for (int i = 0; i < 32; ++i) {
        int e8 = i * 256 + tid;
        int q = e8 >> 6, gc = e8 & 63;
        int grow = (gc >> 4) * Hh + wg_n * 16 + (gc & 15);
        short8 v = *reinterpret_cast<const short8*>(
            whhb + (size_t)grow * Hh + q * 8);
        *reinterpret_cast<short8*>(&Wlds[(q * 64 + gc) * 8]) = v;
    }
    __syncthreads();

    const int row0 = wg_m * 32;
    const int hcol = wg_n * 16 + l15;
    const int lrA = (wave >> 1) * 16 + kq * 4 + ((wave & 1) * 2);
    const int lrB = lrA + 1;
    const int rotsel = (wg_n >> 1) & 3;   // cycles 0..3 within an XCD
    unsigned* myctr = flags + (size_t)(wg_m * 8 + (wg_n >> 3)) * 16;
    float cell0 = 0.f, cell1 = 0.f;

    float xa[2][4], xb[2][4];
    {
        const float* xrA = xg + (size_t)(row0 + lrA) * G + wg_n * 16 + l15;
        #pragma unroll
        for (int nb = 0; nb < 4; ++nb) {
            xa[0][nb] = xrA[nb * Hh];
            xa[1][nb] = xrA[G + nb * Hh];
        }
    }

#define WRC(W_, C_)                                                            \
    if (((C_) >> 1) != (W_)) {                                                 \
        _Pragma("unroll")                                                      \
        for (int nb = 0; nb < 4; ++nb)                                         \
            redsum[((C_) * 3 + (((W_) > ((C_) >> 1)) ? (W_)-1 : (W_))) * 256   \
                   + nb * 64 + lane] = acc[(C_) >> 2][nb][(C_) & 3];           \
    }

#define SPILL(W_)                                                              \
    do {                                                                       \
        _Pragma("unroll")                                                      \
        for (int nb = 0; nb < 4; ++nb) {                                       \
            own0[nb] = acc[(2 * (W_)) >> 2][nb][(2 * (W_)) & 3];               \
            own1[nb] = acc[(2 * (W_) + 1) >> 2][nb][(2 * (W_) + 1) & 3];       \
        }                                                                      \
        WRC(W_, 0); WRC(W_, 1); WRC(W_, 2); WRC(W_, 3);                        \
        WRC(W_, 4); WRC(W_, 5); WRC(W_, 6); WRC(W_, 7);                        \
    } while (0)

#define LSTM_STEP(T, XC, XN)                                                   \
    do {                                                                       \
        const int t_ = (T);                                                    \
        floatx4 acc[2][4];                                                     \
        _Pragma("unroll")                                                      \
        for (int i = 0; i < 2; ++i)                                            \
            _Pragma("unroll")                                                  \
            for (int j = 0; j < 4; ++j) acc[i][j] = (floatx4)0.f;              \
        if (t_ > 0) {                                                          \
            if (tid < 8) {                                                     \
                const unsigned* fl = flags + (size_t)(wg_m * 8 + tid) * 16;    \
                unsigned need = 8u * (unsigned)t_;                             \
                while (__hip_atomic_load(fl, __ATOMIC_RELAXED,                 \
                                         __HIP_MEMORY_SCOPE_AGENT) < need)     \
                    __builtin_amdgcn_s_sleep(1);                               \
            }                                                                  \
            __syncthreads();                                                   \
            asm volatile("" ::: "memory");                                     \
            const unsigned short* hprev = hsb + (size_t)(t_ - 1) * (Bb * Hh);  \
            if (rotsel == 0)                                                   \
                gate_mfma<0>(hprev, Wlds, row0, wave, l15, kq, acc);           \
            else if (rotsel == 1)                                              \
                gate_mfma<2>(hprev, Wlds, row0, wave, l15, kq, acc);           \
            else if (rotsel == 2)                                              \
                gate_mfma<4>(hprev, Wlds, row0, wave, l15, kq, acc);           \
            else                                                               \
                gate_mfma<6>(hprev, Wlds, row0, wave, l15, kq, acc);           \
        }                                                                      \
        float own0[4], own1[4];                                                \
        if (wave == 0)      SPILL(0);                                          \
        else if (wave == 1) SPILL(1);                                          \
        else if (wave == 2) SPILL(2);                                          \
        else                SPILL(3);                                          \
        __syncthreads();                                                       \
        float gA[4], gB[4];                                                    \
        {                                                                      \
            const int cA = wave * 2;                                           \
            _Pragma("unroll")                                                  \
            for (int nb = 0; nb < 4; ++nb) {                                   \
                int bA = (cA * 3) * 256 + nb * 64 + lane;                      \
                gA[nb] = own0[nb] + redsum[bA] + redsum[bA + 256]              \
                       + redsum[bA + 512] + XC[0][nb];                         \
                int bB = ((cA + 1) * 3) * 256 + nb * 64 + lane;                \
                gB[nb] = own1[nb] + redsum[bB] + redsum[bB + 256]              \
                       + redsum[bB + 512] + XC[1][nb];                         \
            }                                                                  \
        }                                                                      \
        unsigned short* ht = hsb + (size_t)t_ * (Bb * Hh);                     \
        {                                                                      \
            float si = sigmoid_fast(gA[0]);                                    \
            float sf = sigmoid_fast(gA[1]);                                    \
            float tg = tanh_fast(gA[2]);                                       \
            float so = sigmoid_fast(gA[3]);                                    \
            float cn = sf * cell0 + si * tg;                                   \
            cell0 = cn;                                                        \
            float h = so * tanh_fast(cn);                                      \
            __hip_atomic_store(&ht[(size_t)(row0 + lrA) * Hh + hcol], f2bf(h), \
                               __ATOMIC_RELAXED, __HIP_MEMORY_SCOPE_AGENT);    \
        }                                                                      \
        {                                                                      \
            float si = sigmoid_fast(gB[0]);                                    \
            float sf = sigmoid_fast(gB[1]);                                    \
            float tg = tanh_fast(gB[2]);                                       \
            float so = sigmoid_fast(gB[3]);                                    \
            float cn = sf * cell1 + si * tg;                                   \
            cell1 = cn;                                                        \
            float h = so * tanh_fast(cn);                                      \
            __hip_atomic_store(&ht[(size_t)(row0 + lrB) * Hh + hcol], f2bf(h), \
                               __ATOMIC_RELAXED, __HIP_MEMORY_SCOPE_AGENT);    \
        }                                                                      \
        __builtin_amdgcn_sched_barrier(0);                                     \
        if (t_ + 1 < Tt) {   /* xg prefetch: YOUNGEST VMEM (after stores) */   \
            const float* xrA = xg + (size_t)(t_ + 1) * (Bb * G)                \
                + (size_t)(row0 + lrA) * G + wg_n * 16 + l15;                  \
            _Pragma("unroll")                                                  \
            for (int nb = 0; nb < 4; ++nb) {                                   \
                XN[0][nb] = xrA[nb * Hh];                                      \
                XN[1][nb] = xrA[G + nb * Hh];                                  \
            }                                                                  \
        }                                                                      \
        __builtin_amdgcn_sched_barrier(0);                                     \
        if (t_ < Tt - 1) {                                                     \
            /* 2 h stores (oldest) + 8 xg loads outstanding: wait stores */    \
            asm volatile("s_waitcnt vmcnt(8)" ::: "memory");                   \
            __builtin_amdgcn_sched_barrier(0);                                 \
            __builtin_amdgcn_s_barrier();                                      \
            __builtin_amdgcn_sched_barrier(0);                                 \
            if (tid == 0)                                                      \
                __hip_atomic_fetch_add(myctr, 1u, __ATOMIC_RELAXED,            \
                                       __HIP_MEMORY_SCOPE_AGENT);              \
        }                                                                      \
    } while (0)

    for (int tt = 0; tt < Tt; tt += 2) {
        LSTM_STEP(tt,     xa, xb);
        LSTM_STEP(tt + 1, xb, xa);
    }
#undef LSTM_STEP
#undef SPILL
#undef WRC
}

// ---------------------------------------------------------------------------
extern "C" void kernel_launch(void* const* d_in, const int* in_sizes, int n_in,
                              void* d_out, int out_size, void* d_ws, size_t ws_size,
                              hipStream_t stream) {
    const float* features = (const float*)d_in[0];
    const int*   captions = (const int*)d_in[1];
    const float* embed_W  = (const float*)d_in[2];
    const float* W_ih     = (const float*)d_in[3];
    const float* W_hh     = (const float*)d_in[4];
    const float* b_ih     = (const float*)d_in[5];
    const float* b_hh     = (const float*)d_in[6];
    const float* fc_W     = (const float*)d_in[7];
    const float* fc_b     = (const float*)d_in[8];
    float* out = (float*)d_out;

    unsigned short* xsb  = (unsigned short*)d_ws;          // [8192][512]
    unsigned short* wihb = xsb  + (size_t)Tt * Bb * Ee;    // [4096][512]
    unsigned short* whhb = wihb + (size_t)G * Ee;          // [4096][1024]
    unsigned short* fcwb = whhb + (size_t)G * Hh;          // [10240][1024]
    unsigned short* hsb  = fcwb + (size_t)Vpad * Hh;       // [64][128][1024]
    float* xg = (float*)(hsb + (size_t)Tt * Bb * Hh);      // [8192][4096]
    unsigned* flags = (unsigned*)(xg + (size_t)Tt * Bb * G); // 32 ctrs, 64B stride

    (void)hipMemsetAsync(flags, 0, 128 * 32 * sizeof(unsigned), stream);

    // 1) weight conversions + input gather
    cvt_bf16<<<(G * Ee / 8) / 256, 256, 0, stream>>>(W_ih, wihb, G * Ee, G * Ee);
    cvt_bf16<<<(G * Hh / 8) / 256, 256, 0, stream>>>(W_hh, whhb, G * Hh, G * Hh);
    cvt_bf16<<<(Vpad * Hh / 8) / 256, 256, 0, stream>>>(fc_W, fcwb, Vv * Hh, Vpad * Hh);
    gather_xs<<<(Tt * Bb * (Ee / 8)) / 256, 256, 0, stream>>>(
        features, captions, embed_W, xsb);

    // 2) x_gates = xs @ W_ih^T + b_ih + b_hh   (M=8192, N=4096, K=512)
    {
        dim3 grid(8192 / 256, G / 256);   // 32 x 16 = 512 wgs (%8 == 0)
        gemm256<0><<<grid, 512, 0, stream>>>(
            xsb, wihb, 8192, G, Ee, b_ih, b_hh, xg);
    }

    // 3) persistent LSTM recurrence (one launch, 64 steps, all 256 CUs)
    lstm_persist<<<256, 256, 0, stream>>>(whhb, xg, hsb, flags);

    // 4) out[b,t,v] = hs @ fc_W^T + fc_b   (M=8192, N=10000(pad 10240), K=1024)
    {
        dim3 grid(8192 / 256, Vpad / 256);  // 32 x 40 = 1280 wgs (%8 == 0)
        gemm256<2><<<grid, 512, 0, stream>>>(
            hsb, fcwb, 8192, Vv, Hh, fc_b, nullptr, out);
    }
}